// Round 13
// baseline (323.080 us; speedup 1.0000x reference)
//
#include <hip/hip_runtime.h>
#include <hip/hip_bf16.h>
#include <cstdint>
#include <cmath>

#define DIM 4096
#define NH 32
#define NKV 8
#define HD 128
#define S_LEN 2048
#define KVD (NKV * HD)   // 1024
#define QS 6144          // fused qkv row stride
#define SCALE 0.08838834764831845f

typedef __attribute__((ext_vector_type(4))) float f32x4;
typedef __attribute__((ext_vector_type(8))) short short8;

__device__ __forceinline__ short f2bf(float f) {
  union { float f; uint32_t u; } v; v.f = f;
  uint32_t u = v.u;
  u += 0x7fffu + ((u >> 16) & 1u);
  return (short)(u >> 16);
}
__device__ __forceinline__ float bf2f(short b) {
  union { uint32_t u; float f; } v; v.u = ((uint32_t)(uint16_t)b) << 16;
  return v.f;
}

__device__ __forceinline__ void async16(const void* g, void* l) {
  __builtin_amdgcn_global_load_lds(
      (__attribute__((address_space(1))) void*)(g),
      (__attribute__((address_space(3))) void*)(l), 16, 0, 0);
}

// ---------------- small prep kernels ----------------

__global__ void rope_tables_k(float* __restrict__ ct, float* __restrict__ st) {
  const int i = blockIdx.x * blockDim.x + threadIdx.x;
  if (i >= S_LEN * 64) return;
  const int s = i >> 6, d = i & 63;
  const float inv = powf(10000.0f, -(float)(2 * d) / 128.0f);
  const float fr = (float)s * inv;
  ct[i] = cosf(fr);
  st[i] = sinf(fr);
}

__global__ void cast_f32_bf16_k(const float* __restrict__ in, short* __restrict__ out, int n4) {
  const int i = blockIdx.x * blockDim.x + threadIdx.x;
  if (i >= n4) return;
  const float4 v = ((const float4*)in)[i];
  short4 o;
  o.x = f2bf(v.x); o.y = f2bf(v.y); o.z = f2bf(v.z); o.w = f2bf(v.w);
  ((short4*)out)[i] = o;
}

// fused + vectorized weight prep: four W [K=4096][N] f32 -> W^T [N][4096] bf16.
// float4 loads (256B/wave-row), LDS [64][65] f32, short8 stores (16B/lane,
// 128B contiguous per 8-lane group). Store-side LDS reads: 8-lane groups spread
// over 4 banks (65*8*4B % 128B) -> 2-way, free (m136).
__global__ __launch_bounds__(256) void prep_w_k(
    const float* __restrict__ wq, const float* __restrict__ wk,
    const float* __restrict__ wv, const float* __restrict__ wo,
    short* __restrict__ wqkvT, short* __restrict__ woT) {
  __shared__ float tile[64][65];
  int b = blockIdx.x;
  const float* src; short* dst; int N, bx, by;
  if (b < 4096)      { src = wq; dst = wqkvT;                        N = 4096; bx = b & 63; by = b >> 6; }
  else if (b < 5120) { b -= 4096; src = wk; dst = wqkvT + (size_t)4096 * DIM; N = 1024; bx = b & 15; by = b >> 4; }
  else if (b < 6144) { b -= 5120; src = wv; dst = wqkvT + (size_t)5120 * DIM; N = 1024; bx = b & 15; by = b >> 4; }
  else               { b -= 6144; src = wo; dst = woT;               N = 4096; bx = b & 63; by = b >> 6; }
  const int r0 = by * 64, c0 = bx * 64;
  const int t = threadIdx.x;
  const int lr = t >> 4, lc = (t & 15) * 4;
#pragma unroll
  for (int j = 0; j < 4; ++j) {
    const float4 v = *(const float4*)(src + (size_t)(r0 + lr + j * 16) * N + c0 + lc);
    tile[lr + j * 16][lc + 0] = v.x;
    tile[lr + j * 16][lc + 1] = v.y;
    tile[lr + j * 16][lc + 2] = v.z;
    tile[lr + j * 16][lc + 3] = v.w;
  }
  __syncthreads();
  const int orr = (t & 7) * 8;   // out cols r0+orr..+7  (= source rows)
  const int oc0 = t >> 3;        // out row within tile, 0..31 (+32)
#pragma unroll
  for (int j = 0; j < 2; ++j) {
    const int oc = oc0 + j * 32;
    short8 o;
#pragma unroll
    for (int k = 0; k < 8; ++k) o[k] = f2bf(tile[orr + k][oc]);
    *(short8*)(dst + (size_t)(c0 + oc) * DIM + r0 + orr) = o;
  }
}

// bf16 transpose: in [R][C] (row stride ldi) -> out [C][R]
__global__ void transpose_bf16_k(const short* __restrict__ in, short* __restrict__ out,
                                 int R, int C, int ldi) {
  __shared__ short tile[32][33];
  const int tx = threadIdx.x, ty = threadIdx.y;
  const int c0 = blockIdx.x * 32, r0 = blockIdx.y * 32;
#pragma unroll
  for (int j = 0; j < 4; ++j)
    tile[ty + j * 8][tx] = in[(size_t)(r0 + ty + j * 8) * ldi + c0 + tx];
  __syncthreads();
#pragma unroll
  for (int j = 0; j < 4; ++j)
    out[(size_t)(c0 + ty + j * 8) * R + r0 + tx] = tile[tx][ty + j * 8];
}

// in-place RoPE on bf16 [S][*] with row stride ld; nheads=40 covers q+k in one pass.
__global__ void rope_apply_k(short* __restrict__ xq, int ld, const float* __restrict__ ct,
                             const float* __restrict__ st, int nheads) {
  const int i = blockIdx.x * blockDim.x + threadIdx.x;
  const int total = S_LEN * nheads * 64;
  if (i >= total) return;
  const int d = i & 63;
  const int t = i >> 6;
  const int hh = t % nheads;
  const int s = t / nheads;
  short* p = xq + (size_t)s * ld + hh * HD + d;
  const float x1 = bf2f(p[0]);
  const float x2 = bf2f(p[64]);
  const float c = ct[(s << 6) + d];
  const float sn = st[(s << 6) + d];
  p[0]  = f2bf(x1 * c - x2 * sn);
  p[64] = f2bf(x2 * c + x1 * sn);
}

// SYNC with counted vmcnt AND counted lgkmcnt.
#define SYNC2(VM, LG)                                            \
  asm volatile("s_waitcnt vmcnt(" #VM ")" ::: "memory");         \
  __builtin_amdgcn_s_barrier();                                  \
  asm volatile("s_waitcnt lgkmcnt(" #LG ")" ::: "memory");       \
  __builtin_amdgcn_sched_barrier(0);                             \
  __builtin_amdgcn_s_setprio(1)

#define PH_END()                                                 \
  __builtin_amdgcn_s_setprio(0);                                 \
  __builtin_amdgcn_sched_barrier(0);                             \
  __builtin_amdgcn_s_barrier()

// ---------------- 256x192 2-PHASE GEMM for QKV (bf16 out), grid = 8x32 = 256 ---------
// (R12-proven: counted vm/lg ledger, stage in reader-free window, tail peeled.)

__global__ __launch_bounds__(512, 2) void gemm192_k(
    const short* __restrict__ A, const short* __restrict__ BT,
    short* __restrict__ C, int M, int N, int K) {
  __shared__ __attribute__((aligned(16))) short ldsA[2][256 * 64];
  __shared__ __attribute__((aligned(16))) short ldsB[2][192 * 64];
  const int tid = threadIdx.x;
  const int l = tid & 63, w = tid >> 6;
  const int wrM = w >> 1, wcN = w & 1;     // 4M x 2N waves
  const int lrow = l & 15, lg = l >> 4;
  const int cofs[2] = {(lg ^ (lrow & 7)) << 3, ((4 + lg) ^ (lrow & 7)) << 3};
  (void)M;

  int bid = blockIdx.x;
  const int cpx = gridDim.x >> 3;          // XCD-chunked bijective (grid % 8 == 0)
  bid = (bid & 7) * cpx + (bid >> 3);
  const int ntn = N / 192;                 // 32
  const int m0 = (bid / ntn) << 8;
  const int n0 = (bid % ntn) * 192;

  auto stageA = [&](int tau) {
    const int k0 = tau << 6;
    short* ad = &ldsA[tau & 1][0];
#pragma unroll
    for (int it = 0; it < 4; ++it) {
      const int e = it * 512 + tid;
      const int row = e >> 3;
      const int js = (e & 7) ^ (row & 7);
      async16(A + (size_t)(m0 + row) * K + k0 + js * 8, ad + e * 8);
    }
  };
  auto stageB = [&](int tau) {
    const int k0 = tau << 6;
    short* bd = &ldsB[tau & 1][0];
#pragma unroll
    for (int it = 0; it < 3; ++it) {
      const int e = it * 512 + tid;
      const int row = e >> 3;
      const int js = (e & 7) ^ (row & 7);
      async16(BT + (size_t)(n0 + row) * K + k0 + js * 8, bd + e * 8);
    }
  };
  auto rdA = [&](short8 (&dst)[4][2], int b) {
    const short* p = &ldsA[b][0];
#pragma unroll
    for (int mi = 0; mi < 4; ++mi) {
      const int row = wrM * 64 + mi * 16 + lrow;
#pragma unroll
      for (int kk = 0; kk < 2; ++kk)
        dst[mi][kk] = *(const short8*)(p + row * 64 + cofs[kk]);
    }
  };
  auto rdB3 = [&](short8 (&dst)[3][2], int b, int h) {
    const short* p = &ldsB[b][0];
#pragma unroll
    for (int ni = 0; ni < 3; ++ni) {
      const int row = wcN * 96 + h * 48 + ni * 16 + lrow;
#pragma unroll
      for (int kk = 0; kk < 2; ++kk)
        dst[ni][kk] = *(const short8*)(p + row * 64 + cofs[kk]);
    }
  };

  f32x4 acc[4][6] = {};
  auto half24 = [&](short8 (&Af)[4][2], int h, short8 (&Bf)[3][2]) {
#pragma unroll
    for (int kk = 0; kk < 2; ++kk)
#pragma unroll
      for (int mi = 0; mi < 4; ++mi)
#pragma unroll
        for (int ni = 0; ni < 3; ++ni)
          acc[mi][h * 3 + ni] = __builtin_amdgcn_mfma_f32_16x16x32_bf16(
              Af[mi][kk], Bf[ni][kk], acc[mi][h * 3 + ni], 0, 0, 0);
  };

  short8 Aa[4][2], Ab[4][2], BF[3][2], BS[3][2];

  // prologue: stage t0 (A4,B3), t1 (A4,B3); vm(7) retires t0; pre-read A(0), BF(0)
  stageA(0); stageB(0); stageA(1); stageB(1);
  asm volatile("s_waitcnt vmcnt(7)" ::: "memory");
  __builtin_amdgcn_s_barrier();
  rdA(Aa, 0); rdB3(BF, 0, 0);

  const int KT = K >> 6;  // 64 (even, >= 4)
  for (int u = 0; u < (KT - 2) / 2; ++u) {
    const int e = 2 * u;
    // ---- tile e (buf0, A=Aa) ----
    rdB3(BS, 0, 1);
    SYNC2(7, 6);  stageA(e + 2); half24(Aa, 0, BF); PH_END();
    SYNC2(4, 0);  stageB(e + 2); rdA(Ab, 1); rdB3(BF, 1, 0);
                  half24(Aa, 1, BS); PH_END();
    // ---- tile e+1 (buf1, A=Ab) ----
    rdB3(BS, 1, 1);
    SYNC2(7, 6);  stageA(e + 3); half24(Ab, 0, BF); PH_END();
    SYNC2(4, 0);  stageB(e + 3); rdA(Aa, 0); rdB3(BF, 0, 0);
                  half24(Ab, 1, BS); PH_END();
  }
  // ---- tail tile KT-2 (buf0, A=Aa): no staging ----
  rdB3(BS, 0, 1);
  SYNC2(7, 6);  half24(Aa, 0, BF); PH_END();     // outstanding: KT-1's 7 -> pass
  SYNC2(0, 0);  rdA(Ab, 1); rdB3(BF, 1, 0);      // vm0 drains KT-1 first
                half24(Aa, 1, BS); PH_END();
  // ---- tile KT-1 (buf1, A=Ab): all resident ----
  rdB3(BS, 1, 1);
  SYNC2(0, 6);  half24(Ab, 0, BF); PH_END();
  SYNC2(0, 0);  half24(Ab, 1, BS); PH_END();

  // epilogue
  const int orow0 = m0 + wrM * 64 + lg * 4;
  const int ocol0 = n0 + wcN * 96 + lrow;
#pragma unroll
  for (int mi = 0; mi < 4; ++mi)
#pragma unroll
    for (int n = 0; n < 6; ++n)
#pragma unroll
      for (int r = 0; r < 4; ++r)
        C[(size_t)(orow0 + mi * 16 + r) * N + (ocol0 + n * 16)] = f2bf(acc[mi][n][r]);
}

// ---------------- 128x256 2-phase GEMM for WO (fp32 out), grid = 16x16 = 256 ---------

__global__ __launch_bounds__(512, 2) void gemm_wo2_k(
    const short* __restrict__ A, const short* __restrict__ BT,
    float* __restrict__ C, int M, int N, int K) {
  __shared__ __attribute__((aligned(16))) short ldsA[2][128 * 64];
  __shared__ __attribute__((aligned(16))) short ldsB[2][256 * 64];
  const int tid = threadIdx.x;
  const int l = tid & 63, w = tid >> 6;
  const int wrM = w >> 2, wcN = w & 3;     // 2M x 4N waves
  const int lrow = l & 15, lg = l >> 4;
  const int cofs[2] = {(lg ^ (lrow & 7)) << 3, ((4 + lg) ^ (lrow & 7)) << 3};
  (void)M;

  int bid = blockIdx.x;
  const int cpx = gridDim.x >> 3;
  bid = (bid & 7) * cpx + (bid >> 3);
  const int ntn = N >> 8;                  // 16
  const int m0 = (bid / ntn) << 7;
  const int n0 = (bid % ntn) << 8;

  auto stageA2 = [&](int tau) {
    const int k0 = tau << 6;
    short* ad = &ldsA[tau & 1][0];
#pragma unroll
    for (int it = 0; it < 2; ++it) {
      const int e = it * 512 + tid;
      const int row = e >> 3;
      const int js = (e & 7) ^ (row & 7);
      async16(A + (size_t)(m0 + row) * K + k0 + js * 8, ad + e * 8);
    }
  };
  auto stageB2 = [&](int tau) {
    const int k0 = tau << 6;
    short* bd = &ldsB[tau & 1][0];
#pragma unroll
    for (int it = 0; it < 4; ++it) {
      const int e = it * 512 + tid;
      const int row = e >> 3;
      const int js = (e & 7) ^ (row & 7);
      async16(BT + (size_t)(n0 + row) * K + k0 + js * 8, bd + e * 8);
    }
  };
  auto rdA = [&](short8 (&dst)[4][2], int b) {
    const short* p = &ldsA[b][0];
#pragma unroll
    for (int mi = 0; mi < 4; ++mi) {
      const int row = wrM * 64 + mi * 16 + lrow;
#pragma unroll
      for (int kk = 0; kk < 2; ++kk)
        dst[mi][kk] = *(const short8*)(p + row * 64 + cofs[kk]);
    }
  };
  auto rdB = [&](short8 (&dst)[2][2], int b, int h) {
    const short* p = &ldsB[b][0];
#pragma unroll
    for (int ni = 0; ni < 2; ++ni) {
      const int row = wcN * 64 + h * 32 + ni * 16 + lrow;
#pragma unroll
      for (int kk = 0; kk < 2; ++kk)
        dst[ni][kk] = *(const short8*)(p + row * 64 + cofs[kk]);
    }
  };

  f32x4 acc[4][4] = {};
  auto half = [&](short8 (&Af)[4][2], int h, short8 (&Bf)[2][2]) {
#pragma unroll
    for (int kk = 0; kk < 2; ++kk)
#pragma unroll
      for (int mi = 0; mi < 4; ++mi)
#pragma unroll
        for (int ni = 0; ni < 2; ++ni)
          acc[mi][h * 2 + ni] = __builtin_amdgcn_mfma_f32_16x16x32_bf16(
              Af[mi][kk], Bf[ni][kk], acc[mi][h * 2 + ni], 0, 0, 0);
  };

  short8 Aa[4][2], Ab[4][2], H0[2][2], H1[2][2];

  // prologue
  stageA2(0); stageB2(0); stageA2(1); stageB2(1);
  asm volatile("s_waitcnt vmcnt(6)" ::: "memory");
  __builtin_amdgcn_s_barrier();
  rdA(Aa, 0); rdB(H0, 0, 0);

  const int KT = K >> 6;  // 64 (even, >= 4)
  for (int u = 0; u < (KT - 2) / 2; ++u) {
    const int e = 2 * u;
    // ---- tile e (buf0, A=Aa) ----
    rdB(H1, 0, 1);
    SYNC2(6, 4);  stageA2(e + 2); half(Aa, 0, H0); PH_END();
    SYNC2(2, 0);  stageB2(e + 2); rdA(Ab, 1); rdB(H0, 1, 0);
                  half(Aa, 1, H1); PH_END();
    // ---- tile e+1 (buf1, A=Ab) ----
    rdB(H1, 1, 1);
    SYNC2(6, 4);  stageA2(e + 3); half(Ab, 0, H0); PH_END();
    SYNC2(2, 0);  stageB2(e + 3); rdA(Aa, 0); rdB(H0, 0, 0);
                  half(Ab, 1, H1); PH_END();
  }
  // ---- tail tile KT-2 (buf0, A=Aa): no staging ----
  rdB(H1, 0, 1);
  SYNC2(6, 4);  half(Aa, 0, H0); PH_END();
  SYNC2(0, 0);  rdA(Ab, 1); rdB(H0, 1, 0);       // vm0 retired KT-1 first
                half(Aa, 1, H1); PH_END();
  // ---- tile KT-1 (buf1, A=Ab) ----
  rdB(H1, 1, 1);
  SYNC2(0, 4);  half(Ab, 0, H0); PH_END();
  SYNC2(0, 0);  half(Ab, 1, H1); PH_END();

  // epilogue (fp32)
  const int orow0 = m0 + wrM * 64 + lg * 4;
  const int ocol0 = n0 + wcN * 64 + lrow;
#pragma unroll
  for (int mi = 0; mi < 4; ++mi)
#pragma unroll
    for (int n = 0; n < 4; ++n)
#pragma unroll
      for (int r = 0; r < 4; ++r)
        C[(size_t)(orow0 + mi * 16 + r) * N + (ocol0 + n * 16)] = acc[mi][n][r];
}

// ---------------- flash attention (causal, GQA 4:1) ----------------

__global__ __launch_bounds__(256, 3) void attn_k(
    const short* __restrict__ Q, const short* __restrict__ Kc,
    const short* __restrict__ VTg, short* __restrict__ O) {
  __shared__ __attribute__((aligned(16))) short Ks[2][64 * 128];
  __shared__ __attribute__((aligned(16))) short Vt[2][128 * 64];
  __shared__ __attribute__((aligned(16))) short Ps[4][32 * 64];

  const int tid = threadIdx.x;
  const int w = tid >> 6, l = tid & 63;
  const int lrow = l & 15, lg = l >> 4;

  int b = blockIdx.x, h, qt;
  if (b < 256) { h = b >> 3; qt = 15 - (b & 7); }
  else { b -= 256; h = b >> 3; qt = b & 7; }
  const int kvh = h >> 2;
  const int qb0 = qt * 128;
  const int qrow0 = qb0 + w * 32;
  const int nkt = 2 * qt + 2;

  short8 qf[2][4];
#pragma unroll
  for (int nq = 0; nq < 2; ++nq) {
    const short* qp = Q + (size_t)(qrow0 + nq * 16 + lrow) * QS + h * HD;
#pragma unroll
    for (int c = 0; c < 4; ++c) qf[nq][c] = *(const short8*)(qp + c * 32 + lg * 8);
  }

  f32x4 o_acc[2][8] = {};
  float m[2] = {-INFINITY, -INFINITY};
  float lsum[2] = {0.f, 0.f};

  auto stage = [&](int kb, int buf) {
    short* kd = Ks[buf];
    short* vd = Vt[buf];
#pragma unroll
    for (int it = 0; it < 4; ++it) {
      const int e = it * 256 + tid;
      const int row = e >> 4, j = e & 15;
      const int jsrc = (j & 8) | ((j ^ row) & 7);
      async16(Kc + (size_t)(kb + row) * QS + kvh * HD + jsrc * 8, kd + e * 8);
    }
#pragma unroll
    for (int it = 0; it < 4; ++it) {
      const int e = it * 256 + tid;
      const int d = e >> 3, j = e & 7;
      const int jsrc = (j ^ d) & 7;
      async16(VTg + (size_t)(kvh * HD + d) * S_LEN + kb + jsrc * 8, vd + e * 8);
    }
  };

  stage(0, 0);
  int cur = 0;

  for (int kt = 0; kt < nkt; ++kt) {
    __syncthreads();
    if (kt + 1 < nkt) stage((kt + 1) * 64, cur ^ 1);
    const int kb = kt * 64;

    if (kb <= qrow0 + 31) {
      const char* ks = (const char*)Ks[cur];
      const char* vt = (const char*)Vt[cur];
      char* psb = (char*)Ps[w];

      f32x4 stq[4][2] = {};
      __builtin_amdgcn_s_setprio(1);
#pragma unroll
      for (int c = 0; c < 4; ++c) {
#pragma unroll
        for (int mk = 0; mk < 4; ++mk) {
          const short8 kf = *(const short8*)(
              ks + (mk * 16 + lrow) * 256 + (((c * 4 + lg) ^ (lrow & 7)) << 4));
          stq[mk][0] = __builtin_amdgcn_mfma_f32_16x16x32_bf16(kf, qf[0][c], stq[mk][0], 0, 0, 0);
          stq[mk][1] = __builtin_amdgcn_mfma_f32_16x16x32_bf16(kf, qf[1][c], stq[mk][1], 0, 0, 0);
        }
      }
      __builtin_amdgcn_s_setprio(0);

      const bool needmask = (kb + 63 > qrow0);
#pragma unroll
      for (int mk = 0; mk < 4; ++mk)
#pragma unroll
        for (int nq = 0; nq < 2; ++nq)
#pragma unroll
          for (int r = 0; r < 4; ++r) {
            float v = stq[mk][nq][r] * SCALE;
            if (needmask && (kb + mk * 16 + lg * 4 + r > qrow0 + nq * 16 + lrow))
              v = -INFINITY;
            stq[mk][nq][r] = v;
          }

      float vmax[2];
#pragma unroll
      for (int nq = 0; nq < 2; ++nq) {
        float v = stq[0][nq][0];
#pragma unroll
        for (int mk = 0; mk < 4; ++mk)
#pragma unroll
          for (int r = 0; r < 4; ++r) v = fmaxf(v, stq[mk][nq][r]);
        v = fmaxf(v, __shfl_xor(v, 16));
        v = fmaxf(v, __shfl_xor(v, 32));
        vmax[nq] = v;
      }

      const int small = (vmax[0] <= m[0] + 8.0f) && (vmax[1] <= m[1] + 8.0f);
      if (!__all(small)) {
        float al[2];
#pragma unroll
        for (int nq = 0; nq < 2; ++nq) {
          const float mn = fmaxf(m[nq], vmax[nq]);
          al[nq] = __expf(m[nq] - mn);
          m[nq] = mn;
          lsum[nq] *= al[nq];
        }
#pragma unroll
        for (int mmq = 0; mmq < 2; ++mmq)
#pragma unroll
          for (int r = 0; r < 4; ++r) {
            const float a = __shfl(al[mmq], lg * 4 + r);
#pragma unroll
            for (int d = 0; d < 8; ++d) o_acc[mmq][d][r] *= a;
          }
      }

      float rs[2] = {0.f, 0.f};
#pragma unroll
      for (int nq = 0; nq < 2; ++nq) {
#pragma unroll
        for (int mk = 0; mk < 4; ++mk) {
          const float p0 = __expf(stq[mk][nq][0] - m[nq]);
          const float p1 = __expf(stq[mk][nq][1] - m[nq]);
          const float p2 = __expf(stq[mk][nq][2] - m[nq]);
          const float p3 = __expf(stq[mk][nq][3] - m[nq]);
          rs[nq] += (p0 + p1) + (p2 + p3);
          __hip_bfloat16 b0 = __float2bfloat16(p0), b1 = __float2bfloat16(p1);
          __hip_bfloat16 b2 = __float2bfloat16(p2), b3 = __float2bfloat16(p3);
          short4 pk;
          pk.x = *(short*)&b0; pk.y = *(short*)&b1; pk.z = *(short*)&b2; pk.w = *(short*)&b3;
          const int q = nq * 16 + lrow;
          *(short4*)(psb + q * 128 + ((mk * 32 + lg * 8) ^ ((q & 7) << 4))) = pk;
        }
        float r2 = rs[nq];
        r2 += __shfl_xor(r2, 16);
        r2 += __shfl_xor(r2, 32);
        lsum[nq] += r2;
      }

      __builtin_amdgcn_s_setprio(1);
#pragma unroll
      for (int cc = 0; cc < 2; ++cc) {
        const int chunk = ((cc * 4 + lg) ^ (lrow & 7)) << 4;
        const short8 pa0 = *(const short8*)(psb + lrow * 128 + chunk);
        const short8 pa1 = *(const short8*)(psb + (16 + lrow) * 128 + chunk);
#pragma unroll
        for (int d = 0; d < 8; ++d) {
          const short8 vf = *(const short8*)(vt + (d * 16 + lrow) * 128 + chunk);
          o_acc[0][d] = __builtin_amdgcn_mfma_f32_16x16x32_bf16(pa0, vf, o_acc[0][d], 0, 0, 0);
          o_acc[1][d] = __builtin_amdgcn_mfma_f32_16x16x32_bf16(pa1, vf, o_acc[1][d], 0, 0, 0);
        }
      }
      __builtin_amdgcn_s_setprio(0);
    }
    cur ^= 1;
  }

  float linv[2] = {1.0f / lsum[0], 1.0f / lsum[1]};
#pragma unroll
  for (int mmq = 0; mmq < 2; ++mmq)
#pragma unroll
    for (int r = 0; r < 4; ++r) {
      const float li = __shfl(linv[mmq], lg * 4 + r);
      short* op = O + (size_t)(qrow0 + mmq * 16 + lg * 4 + r) * DIM + h * HD;
#pragma unroll
      for (int d = 0; d < 8; ++d)
        op[d * 16 + lrow] = f2bf(o_acc[mmq][d][r] * li);
    }
}

// ---------------- launch ----------------

extern "C" void kernel_launch(void* const* d_in, const int* in_sizes, int n_in,
                              void* d_out, int out_size, void* d_ws, size_t ws_size,
                              hipStream_t stream) {
  const float* x  = (const float*)d_in[0];
  const float* wq = (const float*)d_in[1];
  const float* wk = (const float*)d_in[2];
  const float* wv = (const float*)d_in[3];
  const float* wo = (const float*)d_in[4];
  float* out = (float*)d_out;
  (void)in_sizes; (void)n_in; (void)out_size; (void)ws_size;

  char* ws = (char*)d_ws;
  size_t off = 0;
  auto alloc = [&](size_t bytes) -> void* {
    void* p = ws + off;
    off += (bytes + 255) & ~(size_t)255;
    return p;
  };
  short* xb     = (short*)alloc((size_t)S_LEN * DIM * 2);
  short* wqkvT  = (short*)alloc((size_t)QS * DIM * 2);     // [6144][4096]
  short* woT    = (short*)alloc((size_t)DIM * DIM * 2);
  short* qkv    = (short*)alloc((size_t)S_LEN * QS * 2);   // [2048][6144]
  short* vtg    = (short*)alloc((size_t)KVD * S_LEN * 2);  // [1024][2048]
  short* ao     = (short*)alloc((size_t)S_LEN * DIM * 2);
  float* ct     = (float*)alloc((size_t)S_LEN * 64 * 4);
  float* st     = (float*)alloc((size_t)S_LEN * 64 * 4);

  rope_tables_k<<<(S_LEN * 64) / 256, 256, 0, stream>>>(ct, st);
  cast_f32_bf16_k<<<(S_LEN * DIM / 4) / 256, 256, 0, stream>>>(x, xb, S_LEN * DIM / 4);
  prep_w_k<<<dim3(10240), dim3(256), 0, stream>>>(wq, wk, wv, wo, wqkvT, woT);

  // fused QKV projection: [2048][6144], 256x192 2-phase -> grid 256 (full machine)
  gemm192_k<<<dim3((S_LEN / 256) * (QS / 192)), 512, 0, stream>>>(
      xb, wqkvT, qkv, S_LEN, QS, DIM);

  rope_apply_k<<<(S_LEN * 40 * 64) / 256, 256, 0, stream>>>(qkv, QS, ct, st, 40);

  transpose_bf16_k<<<dim3(KVD / 32, S_LEN / 32), dim3(32, 8), 0, stream>>>(
      qkv + 5120, vtg, S_LEN, KVD, QS);

  attn_k<<<dim3(512), 256, 0, stream>>>(qkv, qkv + 4096, vtg, ao);

  // output projection: 128x256 2-phase counted pipeline -> grid 256 (full machine)
  gemm_wo2_k<<<dim3((S_LEN / 128) * (DIM / 256)), 512, 0, stream>>>(
      ao, woT, out, S_LEN, DIM, DIM);
}

// Round 14
// 318.583 us; speedup vs baseline: 1.0141x; 1.0141x over previous
//
#include <hip/hip_runtime.h>
#include <hip/hip_bf16.h>
#include <cstdint>
#include <cmath>

#define DIM 4096
#define NH 32
#define NKV 8
#define HD 128
#define S_LEN 2048
#define KVD (NKV * HD)   // 1024
#define QS 6144          // fused qkv row stride
#define SCALE 0.08838834764831845f

typedef __attribute__((ext_vector_type(4))) float f32x4;
typedef __attribute__((ext_vector_type(8))) short short8;

__device__ __forceinline__ short f2bf(float f) {
  union { float f; uint32_t u; } v; v.f = f;
  uint32_t u = v.u;
  u += 0x7fffu + ((u >> 16) & 1u);
  return (short)(u >> 16);
}
__device__ __forceinline__ float bf2f(short b) {
  union { uint32_t u; float f; } v; v.u = ((uint32_t)(uint16_t)b) << 16;
  return v.f;
}

__device__ __forceinline__ void async16(const void* g, void* l) {
  __builtin_amdgcn_global_load_lds(
      (__attribute__((address_space(1))) void*)(g),
      (__attribute__((address_space(3))) void*)(l), 16, 0, 0);
}

// ---------------- small prep kernels ----------------

__global__ void rope_tables_k(float* __restrict__ ct, float* __restrict__ st) {
  const int i = blockIdx.x * blockDim.x + threadIdx.x;
  if (i >= S_LEN * 64) return;
  const int s = i >> 6, d = i & 63;
  const float inv = powf(10000.0f, -(float)(2 * d) / 128.0f);
  const float fr = (float)s * inv;
  ct[i] = cosf(fr);
  st[i] = sinf(fr);
}

__global__ void cast_f32_bf16_k(const float* __restrict__ in, short* __restrict__ out, int n4) {
  const int i = blockIdx.x * blockDim.x + threadIdx.x;
  if (i >= n4) return;
  const float4 v = ((const float4*)in)[i];
  short4 o;
  o.x = f2bf(v.x); o.y = f2bf(v.y); o.z = f2bf(v.z); o.w = f2bf(v.w);
  ((short4*)out)[i] = o;
}

// fused + vectorized weight prep: four W [K=4096][N] f32 -> W^T [N][4096] bf16.
// float4 loads (256B/wave-row), LDS [64][65] f32, short8 stores (16B/lane).
__global__ __launch_bounds__(256) void prep_w_k(
    const float* __restrict__ wq, const float* __restrict__ wk,
    const float* __restrict__ wv, const float* __restrict__ wo,
    short* __restrict__ wqkvT, short* __restrict__ woT) {
  __shared__ float tile[64][65];
  int b = blockIdx.x;
  const float* src; short* dst; int N, bx, by;
  if (b < 4096)      { src = wq; dst = wqkvT;                        N = 4096; bx = b & 63; by = b >> 6; }
  else if (b < 5120) { b -= 4096; src = wk; dst = wqkvT + (size_t)4096 * DIM; N = 1024; bx = b & 15; by = b >> 4; }
  else if (b < 6144) { b -= 5120; src = wv; dst = wqkvT + (size_t)5120 * DIM; N = 1024; bx = b & 15; by = b >> 4; }
  else               { b -= 6144; src = wo; dst = woT;               N = 4096; bx = b & 63; by = b >> 6; }
  const int r0 = by * 64, c0 = bx * 64;
  const int t = threadIdx.x;
  const int lr = t >> 4, lc = (t & 15) * 4;
#pragma unroll
  for (int j = 0; j < 4; ++j) {
    const float4 v = *(const float4*)(src + (size_t)(r0 + lr + j * 16) * N + c0 + lc);
    tile[lr + j * 16][lc + 0] = v.x;
    tile[lr + j * 16][lc + 1] = v.y;
    tile[lr + j * 16][lc + 2] = v.z;
    tile[lr + j * 16][lc + 3] = v.w;
  }
  __syncthreads();
  const int orr = (t & 7) * 8;   // out cols r0+orr..+7  (= source rows)
  const int oc0 = t >> 3;        // out row within tile, 0..31 (+32)
#pragma unroll
  for (int j = 0; j < 2; ++j) {
    const int oc = oc0 + j * 32;
    short8 o;
#pragma unroll
    for (int k = 0; k < 8; ++k) o[k] = f2bf(tile[orr + k][oc]);
    *(short8*)(dst + (size_t)(c0 + oc) * DIM + r0 + orr) = o;
  }
}

// bf16 transpose: in [R][C] (row stride ldi) -> out [C][R]
__global__ void transpose_bf16_k(const short* __restrict__ in, short* __restrict__ out,
                                 int R, int C, int ldi) {
  __shared__ short tile[32][33];
  const int tx = threadIdx.x, ty = threadIdx.y;
  const int c0 = blockIdx.x * 32, r0 = blockIdx.y * 32;
#pragma unroll
  for (int j = 0; j < 4; ++j)
    tile[ty + j * 8][tx] = in[(size_t)(r0 + ty + j * 8) * ldi + c0 + tx];
  __syncthreads();
#pragma unroll
  for (int j = 0; j < 4; ++j)
    out[(size_t)(c0 + ty + j * 8) * R + r0 + tx] = tile[tx][ty + j * 8];
}

// in-place RoPE on bf16 [S][*] with row stride ld; nheads=40 covers q+k in one pass.
__global__ void rope_apply_k(short* __restrict__ xq, int ld, const float* __restrict__ ct,
                             const float* __restrict__ st, int nheads) {
  const int i = blockIdx.x * blockDim.x + threadIdx.x;
  const int total = S_LEN * nheads * 64;
  if (i >= total) return;
  const int d = i & 63;
  const int t = i >> 6;
  const int hh = t % nheads;
  const int s = t / nheads;
  short* p = xq + (size_t)s * ld + hh * HD + d;
  const float x1 = bf2f(p[0]);
  const float x2 = bf2f(p[64]);
  const float c = ct[(s << 6) + d];
  const float sn = st[(s << 6) + d];
  p[0]  = f2bf(x1 * c - x2 * sn);
  p[64] = f2bf(x2 * c + x1 * sn);
}

// SYNC with counted vmcnt AND counted lgkmcnt.
#define SYNC2(VM, LG)                                            \
  asm volatile("s_waitcnt vmcnt(" #VM ")" ::: "memory");         \
  __builtin_amdgcn_s_barrier();                                  \
  asm volatile("s_waitcnt lgkmcnt(" #LG ")" ::: "memory");       \
  __builtin_amdgcn_sched_barrier(0);                             \
  __builtin_amdgcn_s_setprio(1)

#define PH_END()                                                 \
  __builtin_amdgcn_s_setprio(0);                                 \
  __builtin_amdgcn_sched_barrier(0);                             \
  __builtin_amdgcn_s_barrier()

// ---------------- 256x192 2-PHASE GEMM for QKV (bf16 out), grid = 8x32 = 256 ---------
// (R12-proven: counted vm/lg ledger, stage in reader-free window, tail peeled.)

__global__ __launch_bounds__(512, 2) void gemm192_k(
    const short* __restrict__ A, const short* __restrict__ BT,
    short* __restrict__ C, int M, int N, int K) {
  __shared__ __attribute__((aligned(16))) short ldsA[2][256 * 64];
  __shared__ __attribute__((aligned(16))) short ldsB[2][192 * 64];
  const int tid = threadIdx.x;
  const int l = tid & 63, w = tid >> 6;
  const int wrM = w >> 1, wcN = w & 1;     // 4M x 2N waves
  const int lrow = l & 15, lg = l >> 4;
  const int cofs[2] = {(lg ^ (lrow & 7)) << 3, ((4 + lg) ^ (lrow & 7)) << 3};
  (void)M;

  int bid = blockIdx.x;
  const int cpx = gridDim.x >> 3;          // XCD-chunked bijective (grid % 8 == 0)
  bid = (bid & 7) * cpx + (bid >> 3);
  const int ntn = N / 192;                 // 32
  const int m0 = (bid / ntn) << 8;
  const int n0 = (bid % ntn) * 192;

  auto stageA = [&](int tau) {
    const int k0 = tau << 6;
    short* ad = &ldsA[tau & 1][0];
#pragma unroll
    for (int it = 0; it < 4; ++it) {
      const int e = it * 512 + tid;
      const int row = e >> 3;
      const int js = (e & 7) ^ (row & 7);
      async16(A + (size_t)(m0 + row) * K + k0 + js * 8, ad + e * 8);
    }
  };
  auto stageB = [&](int tau) {
    const int k0 = tau << 6;
    short* bd = &ldsB[tau & 1][0];
#pragma unroll
    for (int it = 0; it < 3; ++it) {
      const int e = it * 512 + tid;
      const int row = e >> 3;
      const int js = (e & 7) ^ (row & 7);
      async16(BT + (size_t)(n0 + row) * K + k0 + js * 8, bd + e * 8);
    }
  };
  auto rdA = [&](short8 (&dst)[4][2], int b) {
    const short* p = &ldsA[b][0];
#pragma unroll
    for (int mi = 0; mi < 4; ++mi) {
      const int row = wrM * 64 + mi * 16 + lrow;
#pragma unroll
      for (int kk = 0; kk < 2; ++kk)
        dst[mi][kk] = *(const short8*)(p + row * 64 + cofs[kk]);
    }
  };
  auto rdB3 = [&](short8 (&dst)[3][2], int b, int h) {
    const short* p = &ldsB[b][0];
#pragma unroll
    for (int ni = 0; ni < 3; ++ni) {
      const int row = wcN * 96 + h * 48 + ni * 16 + lrow;
#pragma unroll
      for (int kk = 0; kk < 2; ++kk)
        dst[ni][kk] = *(const short8*)(p + row * 64 + cofs[kk]);
    }
  };

  f32x4 acc[4][6] = {};
  auto half24 = [&](short8 (&Af)[4][2], int h, short8 (&Bf)[3][2]) {
#pragma unroll
    for (int kk = 0; kk < 2; ++kk)
#pragma unroll
      for (int mi = 0; mi < 4; ++mi)
#pragma unroll
        for (int ni = 0; ni < 3; ++ni)
          acc[mi][h * 3 + ni] = __builtin_amdgcn_mfma_f32_16x16x32_bf16(
              Af[mi][kk], Bf[ni][kk], acc[mi][h * 3 + ni], 0, 0, 0);
  };

  short8 Aa[4][2], Ab[4][2], BF[3][2], BS[3][2];

  // prologue: stage t0 (A4,B3), t1 (A4,B3); vm(7) retires t0; pre-read A(0), BF(0)
  stageA(0); stageB(0); stageA(1); stageB(1);
  asm volatile("s_waitcnt vmcnt(7)" ::: "memory");
  __builtin_amdgcn_s_barrier();
  rdA(Aa, 0); rdB3(BF, 0, 0);

  const int KT = K >> 6;  // 64 (even, >= 4)
  for (int u = 0; u < (KT - 2) / 2; ++u) {
    const int e = 2 * u;
    // ---- tile e (buf0, A=Aa) ----
    rdB3(BS, 0, 1);
    SYNC2(7, 6);  stageA(e + 2); half24(Aa, 0, BF); PH_END();
    SYNC2(4, 0);  stageB(e + 2); rdA(Ab, 1); rdB3(BF, 1, 0);
                  half24(Aa, 1, BS); PH_END();
    // ---- tile e+1 (buf1, A=Ab) ----
    rdB3(BS, 1, 1);
    SYNC2(7, 6);  stageA(e + 3); half24(Ab, 0, BF); PH_END();
    SYNC2(4, 0);  stageB(e + 3); rdA(Aa, 0); rdB3(BF, 0, 0);
                  half24(Ab, 1, BS); PH_END();
  }
  // ---- tail tile KT-2 (buf0, A=Aa): no staging ----
  rdB3(BS, 0, 1);
  SYNC2(7, 6);  half24(Aa, 0, BF); PH_END();     // outstanding: KT-1's 7 -> pass
  SYNC2(0, 0);  rdA(Ab, 1); rdB3(BF, 1, 0);      // vm0 drains KT-1 first
                half24(Aa, 1, BS); PH_END();
  // ---- tile KT-1 (buf1, A=Ab): all resident ----
  rdB3(BS, 1, 1);
  SYNC2(0, 6);  half24(Ab, 0, BF); PH_END();
  SYNC2(0, 0);  half24(Ab, 1, BS); PH_END();

  // epilogue
  const int orow0 = m0 + wrM * 64 + lg * 4;
  const int ocol0 = n0 + wcN * 96 + lrow;
#pragma unroll
  for (int mi = 0; mi < 4; ++mi)
#pragma unroll
    for (int n = 0; n < 6; ++n)
#pragma unroll
      for (int r = 0; r < 4; ++r)
        C[(size_t)(orow0 + mi * 16 + r) * N + (ocol0 + n * 16)] = f2bf(acc[mi][n][r]);
}

// ---------------- 128x256 2-phase GEMM for WO (fp32 out), grid = 16x16 = 256 ---------

__global__ __launch_bounds__(512, 2) void gemm_wo2_k(
    const short* __restrict__ A, const short* __restrict__ BT,
    float* __restrict__ C, int M, int N, int K) {
  __shared__ __attribute__((aligned(16))) short ldsA[2][128 * 64];
  __shared__ __attribute__((aligned(16))) short ldsB[2][256 * 64];
  const int tid = threadIdx.x;
  const int l = tid & 63, w = tid >> 6;
  const int wrM = w >> 2, wcN = w & 3;     // 2M x 4N waves
  const int lrow = l & 15, lg = l >> 4;
  const int cofs[2] = {(lg ^ (lrow & 7)) << 3, ((4 + lg) ^ (lrow & 7)) << 3};
  (void)M;

  int bid = blockIdx.x;
  const int cpx = gridDim.x >> 3;
  bid = (bid & 7) * cpx + (bid >> 3);
  const int ntn = N >> 8;                  // 16
  const int m0 = (bid / ntn) << 7;
  const int n0 = (bid % ntn) << 8;

  auto stageA2 = [&](int tau) {
    const int k0 = tau << 6;
    short* ad = &ldsA[tau & 1][0];
#pragma unroll
    for (int it = 0; it < 2; ++it) {
      const int e = it * 512 + tid;
      const int row = e >> 3;
      const int js = (e & 7) ^ (row & 7);
      async16(A + (size_t)(m0 + row) * K + k0 + js * 8, ad + e * 8);
    }
  };
  auto stageB2 = [&](int tau) {
    const int k0 = tau << 6;
    short* bd = &ldsB[tau & 1][0];
#pragma unroll
    for (int it = 0; it < 4; ++it) {
      const int e = it * 512 + tid;
      const int row = e >> 3;
      const int js = (e & 7) ^ (row & 7);
      async16(BT + (size_t)(n0 + row) * K + k0 + js * 8, bd + e * 8);
    }
  };
  auto rdA = [&](short8 (&dst)[4][2], int b) {
    const short* p = &ldsA[b][0];
#pragma unroll
    for (int mi = 0; mi < 4; ++mi) {
      const int row = wrM * 64 + mi * 16 + lrow;
#pragma unroll
      for (int kk = 0; kk < 2; ++kk)
        dst[mi][kk] = *(const short8*)(p + row * 64 + cofs[kk]);
    }
  };
  auto rdB = [&](short8 (&dst)[2][2], int b, int h) {
    const short* p = &ldsB[b][0];
#pragma unroll
    for (int ni = 0; ni < 2; ++ni) {
      const int row = wcN * 64 + h * 32 + ni * 16 + lrow;
#pragma unroll
      for (int kk = 0; kk < 2; ++kk)
        dst[ni][kk] = *(const short8*)(p + row * 64 + cofs[kk]);
    }
  };

  f32x4 acc[4][4] = {};
  auto half = [&](short8 (&Af)[4][2], int h, short8 (&Bf)[2][2]) {
#pragma unroll
    for (int kk = 0; kk < 2; ++kk)
#pragma unroll
      for (int mi = 0; mi < 4; ++mi)
#pragma unroll
        for (int ni = 0; ni < 2; ++ni)
          acc[mi][h * 2 + ni] = __builtin_amdgcn_mfma_f32_16x16x32_bf16(
              Af[mi][kk], Bf[ni][kk], acc[mi][h * 2 + ni], 0, 0, 0);
  };

  short8 Aa[4][2], Ab[4][2], H0[2][2], H1[2][2];

  // prologue
  stageA2(0); stageB2(0); stageA2(1); stageB2(1);
  asm volatile("s_waitcnt vmcnt(6)" ::: "memory");
  __builtin_amdgcn_s_barrier();
  rdA(Aa, 0); rdB(H0, 0, 0);

  const int KT = K >> 6;  // 64 (even, >= 4)
  for (int u = 0; u < (KT - 2) / 2; ++u) {
    const int e = 2 * u;
    // ---- tile e (buf0, A=Aa) ----
    rdB(H1, 0, 1);
    SYNC2(6, 4);  stageA2(e + 2); half(Aa, 0, H0); PH_END();
    SYNC2(2, 0);  stageB2(e + 2); rdA(Ab, 1); rdB(H0, 1, 0);
                  half(Aa, 1, H1); PH_END();
    // ---- tile e+1 (buf1, A=Ab) ----
    rdB(H1, 1, 1);
    SYNC2(6, 4);  stageA2(e + 3); half(Ab, 0, H0); PH_END();
    SYNC2(2, 0);  stageB2(e + 3); rdA(Aa, 0); rdB(H0, 0, 0);
                  half(Ab, 1, H1); PH_END();
  }
  // ---- tail tile KT-2 (buf0, A=Aa): no staging ----
  rdB(H1, 0, 1);
  SYNC2(6, 4);  half(Aa, 0, H0); PH_END();
  SYNC2(0, 0);  rdA(Ab, 1); rdB(H0, 1, 0);       // vm0 retired KT-1 first
                half(Aa, 1, H1); PH_END();
  // ---- tile KT-1 (buf1, A=Ab) ----
  rdB(H1, 1, 1);
  SYNC2(0, 4);  half(Ab, 0, H0); PH_END();
  SYNC2(0, 0);  half(Ab, 1, H1); PH_END();

  // epilogue (fp32)
  const int orow0 = m0 + wrM * 64 + lg * 4;
  const int ocol0 = n0 + wcN * 64 + lrow;
#pragma unroll
  for (int mi = 0; mi < 4; ++mi)
#pragma unroll
    for (int n = 0; n < 4; ++n)
#pragma unroll
      for (int r = 0; r < 4; ++r)
        C[(size_t)(orow0 + mi * 16 + r) * N + (ocol0 + n * 16)] = acc[mi][n][r];
}

// ---------------- flash attention (causal, GQA 4:1) ----------------

__global__ __launch_bounds__(256, 3) void attn_k(
    const short* __restrict__ Q, const short* __restrict__ Kc,
    const short* __restrict__ VTg, short* __restrict__ O) {
  __shared__ __attribute__((aligned(16))) short Ks[2][64 * 128];
  __shared__ __attribute__((aligned(16))) short Vt[2][128 * 64];
  __shared__ __attribute__((aligned(16))) short Ps[4][32 * 64];

  const int tid = threadIdx.x;
  const int w = tid >> 6, l = tid & 63;
  const int lrow = l & 15, lg = l >> 4;

  int b = blockIdx.x, h, qt;
  if (b < 256) { h = b >> 3; qt = 15 - (b & 7); }
  else { b -= 256; h = b >> 3; qt = b & 7; }
  const int kvh = h >> 2;
  const int qb0 = qt * 128;
  const int qrow0 = qb0 + w * 32;
  const int nkt = 2 * qt + 2;

  short8 qf[2][4];
#pragma unroll
  for (int nq = 0; nq < 2; ++nq) {
    const short* qp = Q + (size_t)(qrow0 + nq * 16 + lrow) * QS + h * HD;
#pragma unroll
    for (int c = 0; c < 4; ++c) qf[nq][c] = *(const short8*)(qp + c * 32 + lg * 8);
  }

  f32x4 o_acc[2][8] = {};
  float m[2] = {-INFINITY, -INFINITY};
  float lsum[2] = {0.f, 0.f};

  auto stage = [&](int kb, int buf) {
    short* kd = Ks[buf];
    short* vd = Vt[buf];
#pragma unroll
    for (int it = 0; it < 4; ++it) {
      const int e = it * 256 + tid;
      const int row = e >> 4, j = e & 15;
      const int jsrc = (j & 8) | ((j ^ row) & 7);
      async16(Kc + (size_t)(kb + row) * QS + kvh * HD + jsrc * 8, kd + e * 8);
    }
#pragma unroll
    for (int it = 0; it < 4; ++it) {
      const int e = it * 256 + tid;
      const int d = e >> 3, j = e & 7;
      const int jsrc = (j ^ d) & 7;
      async16(VTg + (size_t)(kvh * HD + d) * S_LEN + kb + jsrc * 8, vd + e * 8);
    }
  };

  stage(0, 0);
  int cur = 0;

  for (int kt = 0; kt < nkt; ++kt) {
    __syncthreads();
    if (kt + 1 < nkt) stage((kt + 1) * 64, cur ^ 1);
    const int kb = kt * 64;

    if (kb <= qrow0 + 31) {
      const char* ks = (const char*)Ks[cur];
      const char* vt = (const char*)Vt[cur];
      char* psb = (char*)Ps[w];

      f32x4 stq[4][2] = {};
#pragma unroll
      for (int c = 0; c < 4; ++c) {
#pragma unroll
        for (int mk = 0; mk < 4; ++mk) {
          const short8 kf = *(const short8*)(
              ks + (mk * 16 + lrow) * 256 + (((c * 4 + lg) ^ (lrow & 7)) << 4));
          stq[mk][0] = __builtin_amdgcn_mfma_f32_16x16x32_bf16(kf, qf[0][c], stq[mk][0], 0, 0, 0);
          stq[mk][1] = __builtin_amdgcn_mfma_f32_16x16x32_bf16(kf, qf[1][c], stq[mk][1], 0, 0, 0);
        }
      }

      const bool needmask = (kb + 63 > qrow0);
#pragma unroll
      for (int mk = 0; mk < 4; ++mk)
#pragma unroll
        for (int nq = 0; nq < 2; ++nq)
#pragma unroll
          for (int r = 0; r < 4; ++r) {
            float v = stq[mk][nq][r] * SCALE;
            if (needmask && (kb + mk * 16 + lg * 4 + r > qrow0 + nq * 16 + lrow))
              v = -INFINITY;
            stq[mk][nq][r] = v;
          }

      float vmax[2];
#pragma unroll
      for (int nq = 0; nq < 2; ++nq) {
        float v = stq[0][nq][0];
#pragma unroll
        for (int mk = 0; mk < 4; ++mk)
#pragma unroll
          for (int r = 0; r < 4; ++r) v = fmaxf(v, stq[mk][nq][r]);
        v = fmaxf(v, __shfl_xor(v, 16));
        v = fmaxf(v, __shfl_xor(v, 32));
        vmax[nq] = v;
      }

      const int small = (vmax[0] <= m[0] + 8.0f) && (vmax[1] <= m[1] + 8.0f);
      if (!__all(small)) {
        float al[2];
#pragma unroll
        for (int nq = 0; nq < 2; ++nq) {
          const float mn = fmaxf(m[nq], vmax[nq]);
          al[nq] = __expf(m[nq] - mn);
          m[nq] = mn;
          lsum[nq] *= al[nq];
        }
#pragma unroll
        for (int mmq = 0; mmq < 2; ++mmq)
#pragma unroll
          for (int r = 0; r < 4; ++r) {
            const float a = __shfl(al[mmq], lg * 4 + r);
#pragma unroll
            for (int d = 0; d < 8; ++d) o_acc[mmq][d][r] *= a;
          }
      }

      float rs[2] = {0.f, 0.f};
#pragma unroll
      for (int nq = 0; nq < 2; ++nq) {
#pragma unroll
        for (int mk = 0; mk < 4; ++mk) {
          const float p0 = __expf(stq[mk][nq][0] - m[nq]);
          const float p1 = __expf(stq[mk][nq][1] - m[nq]);
          const float p2 = __expf(stq[mk][nq][2] - m[nq]);
          const float p3 = __expf(stq[mk][nq][3] - m[nq]);
          rs[nq] += (p0 + p1) + (p2 + p3);
          __hip_bfloat16 b0 = __float2bfloat16(p0), b1 = __float2bfloat16(p1);
          __hip_bfloat16 b2 = __float2bfloat16(p2), b3 = __float2bfloat16(p3);
          short4 pk;
          pk.x = *(short*)&b0; pk.y = *(short*)&b1; pk.z = *(short*)&b2; pk.w = *(short*)&b3;
          const int q = nq * 16 + lrow;
          *(short4*)(psb + q * 128 + ((mk * 32 + lg * 8) ^ ((q & 7) << 4))) = pk;
        }
        float r2 = rs[nq];
        r2 += __shfl_xor(r2, 16);
        r2 += __shfl_xor(r2, 32);
        lsum[nq] += r2;
      }

#pragma unroll
      for (int cc = 0; cc < 2; ++cc) {
        const int chunk = ((cc * 4 + lg) ^ (lrow & 7)) << 4;
        const short8 pa0 = *(const short8*)(psb + lrow * 128 + chunk);
        const short8 pa1 = *(const short8*)(psb + (16 + lrow) * 128 + chunk);
#pragma unroll
        for (int d = 0; d < 8; ++d) {
          const short8 vf = *(const short8*)(vt + (d * 16 + lrow) * 128 + chunk);
          o_acc[0][d] = __builtin_amdgcn_mfma_f32_16x16x32_bf16(pa0, vf, o_acc[0][d], 0, 0, 0);
          o_acc[1][d] = __builtin_amdgcn_mfma_f32_16x16x32_bf16(pa1, vf, o_acc[1][d], 0, 0, 0);
        }
      }
    }
    cur ^= 1;
  }

  float linv[2] = {1.0f / lsum[0], 1.0f / lsum[1]};
#pragma unroll
  for (int mmq = 0; mmq < 2; ++mmq)
#pragma unroll
    for (int r = 0; r < 4; ++r) {
      const float li = __shfl(linv[mmq], lg * 4 + r);
      short* op = O + (size_t)(qrow0 + mmq * 16 + lg * 4 + r) * DIM + h * HD;
#pragma unroll
      for (int d = 0; d < 8; ++d)
        op[d * 16 + lrow] = f2bf(o_acc[mmq][d][r] * li);
    }
}

// ---------------- launch ----------------

extern "C" void kernel_launch(void* const* d_in, const int* in_sizes, int n_in,
                              void* d_out, int out_size, void* d_ws, size_t ws_size,
                              hipStream_t stream) {
  const float* x  = (const float*)d_in[0];
  const float* wq = (const float*)d_in[1];
  const float* wk = (const float*)d_in[2];
  const float* wv = (const float*)d_in[3];
  const float* wo = (const float*)d_in[4];
  float* out = (float*)d_out;
  (void)in_sizes; (void)n_in; (void)out_size; (void)ws_size;

  char* ws = (char*)d_ws;
  size_t off = 0;
  auto alloc = [&](size_t bytes) -> void* {
    void* p = ws + off;
    off += (bytes + 255) & ~(size_t)255;
    return p;
  };
  short* xb     = (short*)alloc((size_t)S_LEN * DIM * 2);
  short* wqkvT  = (short*)alloc((size_t)QS * DIM * 2);     // [6144][4096]
  short* woT    = (short*)alloc((size_t)DIM * DIM * 2);
  short* qkv    = (short*)alloc((size_t)S_LEN * QS * 2);   // [2048][6144]
  short* vtg    = (short*)alloc((size_t)KVD * S_LEN * 2);  // [1024][2048]
  short* ao     = (short*)alloc((size_t)S_LEN * DIM * 2);
  float* ct     = (float*)alloc((size_t)S_LEN * 64 * 4);
  float* st     = (float*)alloc((size_t)S_LEN * 64 * 4);

  rope_tables_k<<<(S_LEN * 64) / 256, 256, 0, stream>>>(ct, st);
  cast_f32_bf16_k<<<(S_LEN * DIM / 4) / 256, 256, 0, stream>>>(x, xb, S_LEN * DIM / 4);
  prep_w_k<<<dim3(10240), dim3(256), 0, stream>>>(wq, wk, wv, wo, wqkvT, woT);

  // fused QKV projection: [2048][6144], 256x192 2-phase -> grid 256 (full machine)
  gemm192_k<<<dim3((S_LEN / 256) * (QS / 192)), 512, 0, stream>>>(
      xb, wqkvT, qkv, S_LEN, QS, DIM);

  rope_apply_k<<<(S_LEN * 40 * 64) / 256, 256, 0, stream>>>(qkv, QS, ct, st, 40);

  transpose_bf16_k<<<dim3(KVD / 32, S_LEN / 32), dim3(32, 8), 0, stream>>>(
      qkv + 5120, vtg, S_LEN, KVD, QS);

  attn_k<<<dim3(512), 256, 0, stream>>>(qkv, qkv + 4096, vtg, ao);

  // output projection: 128x256 2-phase counted pipeline -> grid 256 (full machine)
  gemm_wo2_k<<<dim3((S_LEN / 128) * (DIM / 256)), 512, 0, stream>>>(
      ao, woT, out, S_LEN, DIM, DIM);
}

// Round 15
// 312.940 us; speedup vs baseline: 1.0324x; 1.0180x over previous
//
#include <hip/hip_runtime.h>
#include <hip/hip_bf16.h>
#include <cstdint>
#include <cmath>

#define DIM 4096
#define NH 32
#define NKV 8
#define HD 128
#define S_LEN 2048
#define KVD (NKV * HD)   // 1024
#define QS 6144          // fused qkv row stride
#define SCALE 0.08838834764831845f

typedef __attribute__((ext_vector_type(4))) float f32x4;
typedef __attribute__((ext_vector_type(8))) short short8;

__device__ __forceinline__ short f2bf(float f) {
  union { float f; uint32_t u; } v; v.f = f;
  uint32_t u = v.u;
  u += 0x7fffu + ((u >> 16) & 1u);
  return (short)(u >> 16);
}
__device__ __forceinline__ float bf2f(short b) {
  union { uint32_t u; float f; } v; v.u = ((uint32_t)(uint16_t)b) << 16;
  return v.f;
}

__device__ __forceinline__ void async16(const void* g, void* l) {
  __builtin_amdgcn_global_load_lds(
      (__attribute__((address_space(1))) void*)(g),
      (__attribute__((address_space(3))) void*)(l), 16, 0, 0);
}

// ---------------- small prep kernels ----------------

__global__ void rope_tables_k(float* __restrict__ ct, float* __restrict__ st) {
  const int i = blockIdx.x * blockDim.x + threadIdx.x;
  if (i >= S_LEN * 64) return;
  const int s = i >> 6, d = i & 63;
  const float inv = powf(10000.0f, -(float)(2 * d) / 128.0f);
  const float fr = (float)s * inv;
  ct[i] = cosf(fr);
  st[i] = sinf(fr);
}

__global__ void cast_f32_bf16_k(const float* __restrict__ in, short* __restrict__ out, int n4) {
  const int i = blockIdx.x * blockDim.x + threadIdx.x;
  if (i >= n4) return;
  const float4 v = ((const float4*)in)[i];
  short4 o;
  o.x = f2bf(v.x); o.y = f2bf(v.y); o.z = f2bf(v.z); o.w = f2bf(v.w);
  ((short4*)out)[i] = o;
}

// fused + vectorized weight prep: four W [K=4096][N] f32 -> W^T [N][4096] bf16.
__global__ __launch_bounds__(256) void prep_w_k(
    const float* __restrict__ wq, const float* __restrict__ wk,
    const float* __restrict__ wv, const float* __restrict__ wo,
    short* __restrict__ wqkvT, short* __restrict__ woT) {
  __shared__ float tile[64][65];
  int b = blockIdx.x;
  const float* src; short* dst; int N, bx, by;
  if (b < 4096)      { src = wq; dst = wqkvT;                        N = 4096; bx = b & 63; by = b >> 6; }
  else if (b < 5120) { b -= 4096; src = wk; dst = wqkvT + (size_t)4096 * DIM; N = 1024; bx = b & 15; by = b >> 4; }
  else if (b < 6144) { b -= 5120; src = wv; dst = wqkvT + (size_t)5120 * DIM; N = 1024; bx = b & 15; by = b >> 4; }
  else               { b -= 6144; src = wo; dst = woT;               N = 4096; bx = b & 63; by = b >> 6; }
  const int r0 = by * 64, c0 = bx * 64;
  const int t = threadIdx.x;
  const int lr = t >> 4, lc = (t & 15) * 4;
#pragma unroll
  for (int j = 0; j < 4; ++j) {
    const float4 v = *(const float4*)(src + (size_t)(r0 + lr + j * 16) * N + c0 + lc);
    tile[lr + j * 16][lc + 0] = v.x;
    tile[lr + j * 16][lc + 1] = v.y;
    tile[lr + j * 16][lc + 2] = v.z;
    tile[lr + j * 16][lc + 3] = v.w;
  }
  __syncthreads();
  const int orr = (t & 7) * 8;
  const int oc0 = t >> 3;
#pragma unroll
  for (int j = 0; j < 2; ++j) {
    const int oc = oc0 + j * 32;
    short8 o;
#pragma unroll
    for (int k = 0; k < 8; ++k) o[k] = f2bf(tile[orr + k][oc]);
    *(short8*)(dst + (size_t)(c0 + oc) * DIM + r0 + orr) = o;
  }
}

// bf16 transpose: in [R][C] (row stride ldi) -> out [C][R]
__global__ void transpose_bf16_k(const short* __restrict__ in, short* __restrict__ out,
                                 int R, int C, int ldi) {
  __shared__ short tile[32][33];
  const int tx = threadIdx.x, ty = threadIdx.y;
  const int c0 = blockIdx.x * 32, r0 = blockIdx.y * 32;
#pragma unroll
  for (int j = 0; j < 4; ++j)
    tile[ty + j * 8][tx] = in[(size_t)(r0 + ty + j * 8) * ldi + c0 + tx];
  __syncthreads();
#pragma unroll
  for (int j = 0; j < 4; ++j)
    out[(size_t)(c0 + ty + j * 8) * R + r0 + tx] = tile[tx][ty + j * 8];
}

// in-place RoPE on bf16 [S][*] with row stride ld; nheads=40 covers q+k in one pass.
__global__ void rope_apply_k(short* __restrict__ xq, int ld, const float* __restrict__ ct,
                             const float* __restrict__ st, int nheads) {
  const int i = blockIdx.x * blockDim.x + threadIdx.x;
  const int total = S_LEN * nheads * 64;
  if (i >= total) return;
  const int d = i & 63;
  const int t = i >> 6;
  const int hh = t % nheads;
  const int s = t / nheads;
  short* p = xq + (size_t)s * ld + hh * HD + d;
  const float x1 = bf2f(p[0]);
  const float x2 = bf2f(p[64]);
  const float c = ct[(s << 6) + d];
  const float sn = st[(s << 6) + d];
  p[0]  = f2bf(x1 * c - x2 * sn);
  p[64] = f2bf(x2 * c + x1 * sn);
}

// SYNC with counted vmcnt AND counted lgkmcnt.
#define SYNC2(VM, LG)                                            \
  asm volatile("s_waitcnt vmcnt(" #VM ")" ::: "memory");         \
  __builtin_amdgcn_s_barrier();                                  \
  asm volatile("s_waitcnt lgkmcnt(" #LG ")" ::: "memory");       \
  __builtin_amdgcn_sched_barrier(0);                             \
  __builtin_amdgcn_s_setprio(1)

#define PH_END()                                                 \
  __builtin_amdgcn_s_setprio(0);                                 \
  __builtin_amdgcn_sched_barrier(0);                             \
  __builtin_amdgcn_s_barrier()

// ---------------- 256x192 2-PHASE GEMM for QKV (bf16 out), grid = 8x32 = 256 ---------
// Equal 3-phase flights for A AND B (the R12 version's B-flight was only 2 phases):
//  p0(t): SYNC(vm7 pass [t+1's 7 in flight], lg0: retires p1(t-1)'s 20 rds)
//         | stageA(t+2)+stageB(t+2) (7 gl -> bufs dead: all t-reads just retired)
//         | MFMA A(t) x BF(t)
//  p1(t): SYNC(vm7: outstanding t+1's 7 + t+2's 7 = 14 -> retires exactly t+1,
//         staged at p0(t-1) = 3-phase flight; lg0 trivial)
//         | rd A(t+1)(8) + BF(t+1)(6) + BS(t+1)(6)  [t+1 resident by vm7+barrier]
//         | MFMA A(t) x BS(t)
// A and BS register sets alternate with tile parity (read-for-t+1 while t's in
// use); BF single-set (BF(t) dead after p0(t)). Tail peeled: KT-2.p1 = vm0
// (drains KT-1; no new stage -> the R6 lesson); KT-1 all-resident.

__global__ __launch_bounds__(512, 2) void gemm192_k(
    const short* __restrict__ A, const short* __restrict__ BT,
    short* __restrict__ C, int M, int N, int K) {
  __shared__ __attribute__((aligned(16))) short ldsA[2][256 * 64];
  __shared__ __attribute__((aligned(16))) short ldsB[2][192 * 64];
  const int tid = threadIdx.x;
  const int l = tid & 63, w = tid >> 6;
  const int wrM = w >> 1, wcN = w & 1;     // 4M x 2N waves
  const int lrow = l & 15, lg = l >> 4;
  const int cofs[2] = {(lg ^ (lrow & 7)) << 3, ((4 + lg) ^ (lrow & 7)) << 3};
  (void)M;

  int bid = blockIdx.x;
  const int cpx = gridDim.x >> 3;          // XCD-chunked bijective (grid % 8 == 0)
  bid = (bid & 7) * cpx + (bid >> 3);
  const int ntn = N / 192;                 // 32
  const int m0 = (bid / ntn) << 8;
  const int n0 = (bid % ntn) * 192;

  auto stageA = [&](int tau) {
    const int k0 = tau << 6;
    short* ad = &ldsA[tau & 1][0];
#pragma unroll
    for (int it = 0; it < 4; ++it) {
      const int e = it * 512 + tid;
      const int row = e >> 3;
      const int js = (e & 7) ^ (row & 7);
      async16(A + (size_t)(m0 + row) * K + k0 + js * 8, ad + e * 8);
    }
  };
  auto stageB = [&](int tau) {
    const int k0 = tau << 6;
    short* bd = &ldsB[tau & 1][0];
#pragma unroll
    for (int it = 0; it < 3; ++it) {
      const int e = it * 512 + tid;
      const int row = e >> 3;
      const int js = (e & 7) ^ (row & 7);
      async16(BT + (size_t)(n0 + row) * K + k0 + js * 8, bd + e * 8);
    }
  };
  auto rdA = [&](short8 (&dst)[4][2], int b) {
    const short* p = &ldsA[b][0];
#pragma unroll
    for (int mi = 0; mi < 4; ++mi) {
      const int row = wrM * 64 + mi * 16 + lrow;
#pragma unroll
      for (int kk = 0; kk < 2; ++kk)
        dst[mi][kk] = *(const short8*)(p + row * 64 + cofs[kk]);
    }
  };
  auto rdB3 = [&](short8 (&dst)[3][2], int b, int h) {
    const short* p = &ldsB[b][0];
#pragma unroll
    for (int ni = 0; ni < 3; ++ni) {
      const int row = wcN * 96 + h * 48 + ni * 16 + lrow;
#pragma unroll
      for (int kk = 0; kk < 2; ++kk)
        dst[ni][kk] = *(const short8*)(p + row * 64 + cofs[kk]);
    }
  };

  f32x4 acc[4][6] = {};
  auto half24 = [&](short8 (&Af)[4][2], int h, short8 (&Bf)[3][2]) {
#pragma unroll
    for (int kk = 0; kk < 2; ++kk)
#pragma unroll
      for (int mi = 0; mi < 4; ++mi)
#pragma unroll
        for (int ni = 0; ni < 3; ++ni)
          acc[mi][h * 3 + ni] = __builtin_amdgcn_mfma_f32_16x16x32_bf16(
              Af[mi][kk], Bf[ni][kk], acc[mi][h * 3 + ni], 0, 0, 0);
  };

  short8 Aa[4][2], Ab[4][2], BF[3][2], BSa[3][2], BSb[3][2];

  // prologue: stage t0, t1; vm7 retires t0; read A(0), BF(0), BS(0)
  stageA(0); stageB(0); stageA(1); stageB(1);
  asm volatile("s_waitcnt vmcnt(7)" ::: "memory");
  __builtin_amdgcn_s_barrier();
  rdA(Aa, 0); rdB3(BF, 0, 0); rdB3(BSa, 0, 1);

  const int KT = K >> 6;  // 64 (even, >= 4)
  for (int u = 0; u < (KT - 2) / 2; ++u) {
    const int e = 2 * u;
    // ---- tile e (buf0, A=Aa, BS=BSa; read t+1 into Ab/BSb) ----
    SYNC2(7, 0);  stageA(e + 2); stageB(e + 2);
                  half24(Aa, 0, BF); PH_END();
    SYNC2(7, 0);  rdA(Ab, 1); rdB3(BF, 1, 0); rdB3(BSb, 1, 1);
                  half24(Aa, 1, BSa); PH_END();
    // ---- tile e+1 (buf1, A=Ab, BS=BSb; read t+2 into Aa/BSa) ----
    SYNC2(7, 0);  stageA(e + 3); stageB(e + 3);
                  half24(Ab, 0, BF); PH_END();
    SYNC2(7, 0);  rdA(Aa, 0); rdB3(BF, 0, 0); rdB3(BSa, 0, 1);
                  half24(Ab, 1, BSb); PH_END();
  }
  // ---- tail tile KT-2 (even: buf0, A=Aa, BS=BSa): no staging ----
  SYNC2(7, 0);  half24(Aa, 0, BF); PH_END();     // outstanding: KT-1's 7 -> pass
  SYNC2(0, 0);  rdA(Ab, 1); rdB3(BF, 1, 0); rdB3(BSb, 1, 1);   // vm0 drains KT-1
                half24(Aa, 1, BSa); PH_END();
  // ---- tile KT-1 (buf1, A=Ab, BS=BSb): all resident ----
  SYNC2(0, 0);  half24(Ab, 0, BF); PH_END();
  SYNC2(0, 0);  half24(Ab, 1, BSb); PH_END();

  // epilogue
  const int orow0 = m0 + wrM * 64 + lg * 4;
  const int ocol0 = n0 + wcN * 96 + lrow;
#pragma unroll
  for (int mi = 0; mi < 4; ++mi)
#pragma unroll
    for (int n = 0; n < 6; ++n)
#pragma unroll
      for (int r = 0; r < 4; ++r)
        C[(size_t)(orow0 + mi * 16 + r) * N + (ocol0 + n * 16)] = f2bf(acc[mi][n][r]);
}

// ---------------- 128x256 2-phase GEMM for WO (fp32 out), grid = 16x16 = 256 ---------
// Same equal-flight transform: all reads at p1 (A 8 + H0 4 + H1 4), both stage
// halves at p0 (6 gl). vm ledger: p1 vm6 retires exactly t+1 (3-phase flight).

__global__ __launch_bounds__(512, 2) void gemm_wo2_k(
    const short* __restrict__ A, const short* __restrict__ BT,
    float* __restrict__ C, int M, int N, int K) {
  __shared__ __attribute__((aligned(16))) short ldsA[2][128 * 64];
  __shared__ __attribute__((aligned(16))) short ldsB[2][256 * 64];
  const int tid = threadIdx.x;
  const int l = tid & 63, w = tid >> 6;
  const int wrM = w >> 2, wcN = w & 3;     // 2M x 4N waves
  const int lrow = l & 15, lg = l >> 4;
  const int cofs[2] = {(lg ^ (lrow & 7)) << 3, ((4 + lg) ^ (lrow & 7)) << 3};
  (void)M;

  int bid = blockIdx.x;
  const int cpx = gridDim.x >> 3;
  bid = (bid & 7) * cpx + (bid >> 3);
  const int ntn = N >> 8;                  // 16
  const int m0 = (bid / ntn) << 7;
  const int n0 = (bid % ntn) << 8;

  auto stageA2 = [&](int tau) {
    const int k0 = tau << 6;
    short* ad = &ldsA[tau & 1][0];
#pragma unroll
    for (int it = 0; it < 2; ++it) {
      const int e = it * 512 + tid;
      const int row = e >> 3;
      const int js = (e & 7) ^ (row & 7);
      async16(A + (size_t)(m0 + row) * K + k0 + js * 8, ad + e * 8);
    }
  };
  auto stageB2 = [&](int tau) {
    const int k0 = tau << 6;
    short* bd = &ldsB[tau & 1][0];
#pragma unroll
    for (int it = 0; it < 4; ++it) {
      const int e = it * 512 + tid;
      const int row = e >> 3;
      const int js = (e & 7) ^ (row & 7);
      async16(BT + (size_t)(n0 + row) * K + k0 + js * 8, bd + e * 8);
    }
  };
  auto rdA = [&](short8 (&dst)[4][2], int b) {
    const short* p = &ldsA[b][0];
#pragma unroll
    for (int mi = 0; mi < 4; ++mi) {
      const int row = wrM * 64 + mi * 16 + lrow;
#pragma unroll
      for (int kk = 0; kk < 2; ++kk)
        dst[mi][kk] = *(const short8*)(p + row * 64 + cofs[kk]);
    }
  };
  auto rdB = [&](short8 (&dst)[2][2], int b, int h) {
    const short* p = &ldsB[b][0];
#pragma unroll
    for (int ni = 0; ni < 2; ++ni) {
      const int row = wcN * 64 + h * 32 + ni * 16 + lrow;
#pragma unroll
      for (int kk = 0; kk < 2; ++kk)
        dst[ni][kk] = *(const short8*)(p + row * 64 + cofs[kk]);
    }
  };

  f32x4 acc[4][4] = {};
  auto half = [&](short8 (&Af)[4][2], int h, short8 (&Bf)[2][2]) {
#pragma unroll
    for (int kk = 0; kk < 2; ++kk)
#pragma unroll
      for (int mi = 0; mi < 4; ++mi)
#pragma unroll
        for (int ni = 0; ni < 2; ++ni)
          acc[mi][h * 2 + ni] = __builtin_amdgcn_mfma_f32_16x16x32_bf16(
              Af[mi][kk], Bf[ni][kk], acc[mi][h * 2 + ni], 0, 0, 0);
  };

  short8 Aa[4][2], Ab[4][2], H0[2][2], H1a[2][2], H1b[2][2];

  // prologue
  stageA2(0); stageB2(0); stageA2(1); stageB2(1);
  asm volatile("s_waitcnt vmcnt(6)" ::: "memory");
  __builtin_amdgcn_s_barrier();
  rdA(Aa, 0); rdB(H0, 0, 0); rdB(H1a, 0, 1);

  const int KT = K >> 6;  // 64 (even, >= 4)
  for (int u = 0; u < (KT - 2) / 2; ++u) {
    const int e = 2 * u;
    // ---- tile e (buf0, A=Aa, H1=H1a) ----
    SYNC2(6, 0);  stageA2(e + 2); stageB2(e + 2);
                  half(Aa, 0, H0); PH_END();
    SYNC2(6, 0);  rdA(Ab, 1); rdB(H0, 1, 0); rdB(H1b, 1, 1);
                  half(Aa, 1, H1a); PH_END();
    // ---- tile e+1 (buf1, A=Ab, H1=H1b) ----
    SYNC2(6, 0);  stageA2(e + 3); stageB2(e + 3);
                  half(Ab, 0, H0); PH_END();
    SYNC2(6, 0);  rdA(Aa, 0); rdB(H0, 0, 0); rdB(H1a, 0, 1);
                  half(Ab, 1, H1b); PH_END();
  }
  // ---- tail tile KT-2 (buf0, A=Aa, H1=H1a): no staging ----
  SYNC2(6, 0);  half(Aa, 0, H0); PH_END();
  SYNC2(0, 0);  rdA(Ab, 1); rdB(H0, 1, 0); rdB(H1b, 1, 1);   // vm0 drains KT-1
                half(Aa, 1, H1a); PH_END();
  // ---- tile KT-1 (buf1, A=Ab, H1=H1b) ----
  SYNC2(0, 0);  half(Ab, 0, H0); PH_END();
  SYNC2(0, 0);  half(Ab, 1, H1b); PH_END();

  // epilogue (fp32)
  const int orow0 = m0 + wrM * 64 + lg * 4;
  const int ocol0 = n0 + wcN * 64 + lrow;
#pragma unroll
  for (int mi = 0; mi < 4; ++mi)
#pragma unroll
    for (int n = 0; n < 4; ++n)
#pragma unroll
      for (int r = 0; r < 4; ++r)
        C[(size_t)(orow0 + mi * 16 + r) * N + (ocol0 + n * 16)] = acc[mi][n][r];
}

// ---------------- flash attention (causal, GQA 4:1) ----------------

__global__ __launch_bounds__(256, 3) void attn_k(
    const short* __restrict__ Q, const short* __restrict__ Kc,
    const short* __restrict__ VTg, short* __restrict__ O) {
  __shared__ __attribute__((aligned(16))) short Ks[2][64 * 128];
  __shared__ __attribute__((aligned(16))) short Vt[2][128 * 64];
  __shared__ __attribute__((aligned(16))) short Ps[4][32 * 64];

  const int tid = threadIdx.x;
  const int w = tid >> 6, l = tid & 63;
  const int lrow = l & 15, lg = l >> 4;

  int b = blockIdx.x, h, qt;
  if (b < 256) { h = b >> 3; qt = 15 - (b & 7); }
  else { b -= 256; h = b >> 3; qt = b & 7; }
  const int kvh = h >> 2;
  const int qb0 = qt * 128;
  const int qrow0 = qb0 + w * 32;
  const int nkt = 2 * qt + 2;

  short8 qf[2][4];
#pragma unroll
  for (int nq = 0; nq < 2; ++nq) {
    const short* qp = Q + (size_t)(qrow0 + nq * 16 + lrow) * QS + h * HD;
#pragma unroll
    for (int c = 0; c < 4; ++c) qf[nq][c] = *(const short8*)(qp + c * 32 + lg * 8);
  }

  f32x4 o_acc[2][8] = {};
  float m[2] = {-INFINITY, -INFINITY};
  float lsum[2] = {0.f, 0.f};

  auto stage = [&](int kb, int buf) {
    short* kd = Ks[buf];
    short* vd = Vt[buf];
#pragma unroll
    for (int it = 0; it < 4; ++it) {
      const int e = it * 256 + tid;
      const int row = e >> 4, j = e & 15;
      const int jsrc = (j & 8) | ((j ^ row) & 7);
      async16(Kc + (size_t)(kb + row) * QS + kvh * HD + jsrc * 8, kd + e * 8);
    }
#pragma unroll
    for (int it = 0; it < 4; ++it) {
      const int e = it * 256 + tid;
      const int d = e >> 3, j = e & 7;
      const int jsrc = (j ^ d) & 7;
      async16(VTg + (size_t)(kvh * HD + d) * S_LEN + kb + jsrc * 8, vd + e * 8);
    }
  };

  stage(0, 0);
  int cur = 0;

  for (int kt = 0; kt < nkt; ++kt) {
    __syncthreads();
    if (kt + 1 < nkt) stage((kt + 1) * 64, cur ^ 1);
    const int kb = kt * 64;

    if (kb <= qrow0 + 31) {
      const char* ks = (const char*)Ks[cur];
      const char* vt = (const char*)Vt[cur];
      char* psb = (char*)Ps[w];

      f32x4 stq[4][2] = {};
#pragma unroll
      for (int c = 0; c < 4; ++c) {
#pragma unroll
        for (int mk = 0; mk < 4; ++mk) {
          const short8 kf = *(const short8*)(
              ks + (mk * 16 + lrow) * 256 + (((c * 4 + lg) ^ (lrow & 7)) << 4));
          stq[mk][0] = __builtin_amdgcn_mfma_f32_16x16x32_bf16(kf, qf[0][c], stq[mk][0], 0, 0, 0);
          stq[mk][1] = __builtin_amdgcn_mfma_f32_16x16x32_bf16(kf, qf[1][c], stq[mk][1], 0, 0, 0);
        }
      }

      const bool needmask = (kb + 63 > qrow0);
#pragma unroll
      for (int mk = 0; mk < 4; ++mk)
#pragma unroll
        for (int nq = 0; nq < 2; ++nq)
#pragma unroll
          for (int r = 0; r < 4; ++r) {
            float v = stq[mk][nq][r] * SCALE;
            if (needmask && (kb + mk * 16 + lg * 4 + r > qrow0 + nq * 16 + lrow))
              v = -INFINITY;
            stq[mk][nq][r] = v;
          }

      float vmax[2];
#pragma unroll
      for (int nq = 0; nq < 2; ++nq) {
        float v = stq[0][nq][0];
#pragma unroll
        for (int mk = 0; mk < 4; ++mk)
#pragma unroll
          for (int r = 0; r < 4; ++r) v = fmaxf(v, stq[mk][nq][r]);
        v = fmaxf(v, __shfl_xor(v, 16));
        v = fmaxf(v, __shfl_xor(v, 32));
        vmax[nq] = v;
      }

      const int small = (vmax[0] <= m[0] + 8.0f) && (vmax[1] <= m[1] + 8.0f);
      if (!__all(small)) {
        float al[2];
#pragma unroll
        for (int nq = 0; nq < 2; ++nq) {
          const float mn = fmaxf(m[nq], vmax[nq]);
          al[nq] = __expf(m[nq] - mn);
          m[nq] = mn;
          lsum[nq] *= al[nq];
        }
#pragma unroll
        for (int mmq = 0; mmq < 2; ++mmq)
#pragma unroll
          for (int r = 0; r < 4; ++r) {
            const float a = __shfl(al[mmq], lg * 4 + r);
#pragma unroll
            for (int d = 0; d < 8; ++d) o_acc[mmq][d][r] *= a;
          }
      }

      float rs[2] = {0.f, 0.f};
#pragma unroll
      for (int nq = 0; nq < 2; ++nq) {
#pragma unroll
        for (int mk = 0; mk < 4; ++mk) {
          const float p0 = __expf(stq[mk][nq][0] - m[nq]);
          const float p1 = __expf(stq[mk][nq][1] - m[nq]);
          const float p2 = __expf(stq[mk][nq][2] - m[nq]);
          const float p3 = __expf(stq[mk][nq][3] - m[nq]);
          rs[nq] += (p0 + p1) + (p2 + p3);
          __hip_bfloat16 b0 = __float2bfloat16(p0), b1 = __float2bfloat16(p1);
          __hip_bfloat16 b2 = __float2bfloat16(p2), b3 = __float2bfloat16(p3);
          short4 pk;
          pk.x = *(short*)&b0; pk.y = *(short*)&b1; pk.z = *(short*)&b2; pk.w = *(short*)&b3;
          const int q = nq * 16 + lrow;
          *(short4*)(psb + q * 128 + ((mk * 32 + lg * 8) ^ ((q & 7) << 4))) = pk;
        }
        float r2 = rs[nq];
        r2 += __shfl_xor(r2, 16);
        r2 += __shfl_xor(r2, 32);
        lsum[nq] += r2;
      }

#pragma unroll
      for (int cc = 0; cc < 2; ++cc) {
        const int chunk = ((cc * 4 + lg) ^ (lrow & 7)) << 4;
        const short8 pa0 = *(const short8*)(psb + lrow * 128 + chunk);
        const short8 pa1 = *(const short8*)(psb + (16 + lrow) * 128 + chunk);
#pragma unroll
        for (int d = 0; d < 8; ++d) {
          const short8 vf = *(const short8*)(vt + (d * 16 + lrow) * 128 + chunk);
          o_acc[0][d] = __builtin_amdgcn_mfma_f32_16x16x32_bf16(pa0, vf, o_acc[0][d], 0, 0, 0);
          o_acc[1][d] = __builtin_amdgcn_mfma_f32_16x16x32_bf16(pa1, vf, o_acc[1][d], 0, 0, 0);
        }
      }
    }
    cur ^= 1;
  }

  float linv[2] = {1.0f / lsum[0], 1.0f / lsum[1]};
#pragma unroll
  for (int mmq = 0; mmq < 2; ++mmq)
#pragma unroll
    for (int r = 0; r < 4; ++r) {
      const float li = __shfl(linv[mmq], lg * 4 + r);
      short* op = O + (size_t)(qrow0 + mmq * 16 + lg * 4 + r) * DIM + h * HD;
#pragma unroll
      for (int d = 0; d < 8; ++d)
        op[d * 16 + lrow] = f2bf(o_acc[mmq][d][r] * li);
    }
}

// ---------------- launch ----------------

extern "C" void kernel_launch(void* const* d_in, const int* in_sizes, int n_in,
                              void* d_out, int out_size, void* d_ws, size_t ws_size,
                              hipStream_t stream) {
  const float* x  = (const float*)d_in[0];
  const float* wq = (const float*)d_in[1];
  const float* wk = (const float*)d_in[2];
  const float* wv = (const float*)d_in[3];
  const float* wo = (const float*)d_in[4];
  float* out = (float*)d_out;
  (void)in_sizes; (void)n_in; (void)out_size; (void)ws_size;

  char* ws = (char*)d_ws;
  size_t off = 0;
  auto alloc = [&](size_t bytes) -> void* {
    void* p = ws + off;
    off += (bytes + 255) & ~(size_t)255;
    return p;
  };
  short* xb     = (short*)alloc((size_t)S_LEN * DIM * 2);
  short* wqkvT  = (short*)alloc((size_t)QS * DIM * 2);     // [6144][4096]
  short* woT    = (short*)alloc((size_t)DIM * DIM * 2);
  short* qkv    = (short*)alloc((size_t)S_LEN * QS * 2);   // [2048][6144]
  short* vtg    = (short*)alloc((size_t)KVD * S_LEN * 2);  // [1024][2048]
  short* ao     = (short*)alloc((size_t)S_LEN * DIM * 2);
  float* ct     = (float*)alloc((size_t)S_LEN * 64 * 4);
  float* st     = (float*)alloc((size_t)S_LEN * 64 * 4);

  rope_tables_k<<<(S_LEN * 64) / 256, 256, 0, stream>>>(ct, st);
  cast_f32_bf16_k<<<(S_LEN * DIM / 4) / 256, 256, 0, stream>>>(x, xb, S_LEN * DIM / 4);
  prep_w_k<<<dim3(10240), dim3(256), 0, stream>>>(wq, wk, wv, wo, wqkvT, woT);

  // fused QKV projection: [2048][6144], 256x192 2-phase -> grid 256 (full machine)
  gemm192_k<<<dim3((S_LEN / 256) * (QS / 192)), 512, 0, stream>>>(
      xb, wqkvT, qkv, S_LEN, QS, DIM);

  rope_apply_k<<<(S_LEN * 40 * 64) / 256, 256, 0, stream>>>(qkv, QS, ct, st, 40);

  transpose_bf16_k<<<dim3(KVD / 32, S_LEN / 32), dim3(32, 8), 0, stream>>>(
      qkv + 5120, vtg, S_LEN, KVD, QS);

  attn_k<<<dim3(512), 256, 0, stream>>>(qkv, qkv + 4096, vtg, ao);

  // output projection: 128x256 2-phase counted pipeline -> grid 256 (full machine)
  gemm_wo2_k<<<dim3((S_LEN / 128) * (DIM / 256)), 512, 0, stream>>>(
      ao, woT, out, S_LEN, DIM, DIM);
}

// Round 16
// 304.853 us; speedup vs baseline: 1.0598x; 1.0265x over previous
//
#include <hip/hip_runtime.h>
#include <hip/hip_bf16.h>
#include <cstdint>
#include <cmath>

#define DIM 4096
#define NH 32
#define NKV 8
#define HD 128
#define S_LEN 2048
#define KVD (NKV * HD)   // 1024
#define QS 6144          // fused qkv row stride
#define SCALE 0.08838834764831845f

typedef __attribute__((ext_vector_type(4))) float f32x4;
typedef __attribute__((ext_vector_type(8))) short short8;

__device__ __forceinline__ short f2bf(float f) {
  union { float f; uint32_t u; } v; v.f = f;
  uint32_t u = v.u;
  u += 0x7fffu + ((u >> 16) & 1u);
  return (short)(u >> 16);
}
__device__ __forceinline__ float bf2f(short b) {
  union { uint32_t u; float f; } v; v.u = ((uint32_t)(uint16_t)b) << 16;
  return v.f;
}

__device__ __forceinline__ void async16(const void* g, void* l) {
  __builtin_amdgcn_global_load_lds(
      (__attribute__((address_space(1))) void*)(g),
      (__attribute__((address_space(3))) void*)(l), 16, 0, 0);
}

// ---------------- small prep kernels ----------------

__global__ void rope_tables_k(float* __restrict__ ct, float* __restrict__ st) {
  const int i = blockIdx.x * blockDim.x + threadIdx.x;
  if (i >= S_LEN * 64) return;
  const int s = i >> 6, d = i & 63;
  const float inv = powf(10000.0f, -(float)(2 * d) / 128.0f);
  const float fr = (float)s * inv;
  ct[i] = cosf(fr);
  st[i] = sinf(fr);
}

__global__ void cast_f32_bf16_k(const float* __restrict__ in, short* __restrict__ out, int n4) {
  const int i = blockIdx.x * blockDim.x + threadIdx.x;
  if (i >= n4) return;
  const float4 v = ((const float4*)in)[i];
  short4 o;
  o.x = f2bf(v.x); o.y = f2bf(v.y); o.z = f2bf(v.z); o.w = f2bf(v.w);
  ((short4*)out)[i] = o;
}

// fused + vectorized weight prep: four W [K=4096][N] f32 -> W^T [N][4096] bf16.
__global__ __launch_bounds__(256) void prep_w_k(
    const float* __restrict__ wq, const float* __restrict__ wk,
    const float* __restrict__ wv, const float* __restrict__ wo,
    short* __restrict__ wqkvT, short* __restrict__ woT) {
  __shared__ float tile[64][65];
  int b = blockIdx.x;
  const float* src; short* dst; int N, bx, by;
  if (b < 4096)      { src = wq; dst = wqkvT;                        N = 4096; bx = b & 63; by = b >> 6; }
  else if (b < 5120) { b -= 4096; src = wk; dst = wqkvT + (size_t)4096 * DIM; N = 1024; bx = b & 15; by = b >> 4; }
  else if (b < 6144) { b -= 5120; src = wv; dst = wqkvT + (size_t)5120 * DIM; N = 1024; bx = b & 15; by = b >> 4; }
  else               { b -= 6144; src = wo; dst = woT;               N = 4096; bx = b & 63; by = b >> 6; }
  const int r0 = by * 64, c0 = bx * 64;
  const int t = threadIdx.x;
  const int lr = t >> 4, lc = (t & 15) * 4;
#pragma unroll
  for (int j = 0; j < 4; ++j) {
    const float4 v = *(const float4*)(src + (size_t)(r0 + lr + j * 16) * N + c0 + lc);
    tile[lr + j * 16][lc + 0] = v.x;
    tile[lr + j * 16][lc + 1] = v.y;
    tile[lr + j * 16][lc + 2] = v.z;
    tile[lr + j * 16][lc + 3] = v.w;
  }
  __syncthreads();
  const int orr = (t & 7) * 8;
  const int oc0 = t >> 3;
#pragma unroll
  for (int j = 0; j < 2; ++j) {
    const int oc = oc0 + j * 32;
    short8 o;
#pragma unroll
    for (int k = 0; k < 8; ++k) o[k] = f2bf(tile[orr + k][oc]);
    *(short8*)(dst + (size_t)(c0 + oc) * DIM + r0 + orr) = o;
  }
}

// fused RoPE (vectorized, short8 = 8 dims/lane) + V^T transpose, one launch.
// blocks [0,2560): rope over q+k heads (cols 0..5119, 40 "heads").
// blocks [2560,4608): 32x32 tile transpose of V cols (5120..6143) -> vtg[1024][2048].
__global__ __launch_bounds__(256) void rope_vt_k(
    short* __restrict__ qkv, const float* __restrict__ ct,
    const float* __restrict__ st, short* __restrict__ vtg) {
  __shared__ short tile[32][33];
  int b = blockIdx.x;
  if (b < 2560) {
    const int i = b * 256 + threadIdx.x;   // 655360 = 2048*40*8 exactly
    const int d0 = (i & 7) * 8;
    const int t = i >> 3;
    const int hh = t % 40;
    const int s = t / 40;
    short* p = qkv + (size_t)s * QS + hh * HD + d0;
    const short8 x1 = *(const short8*)p;
    const short8 x2 = *(const short8*)(p + 64);
    const float* cb = ct + (s << 6) + d0;
    const float* sb = st + (s << 6) + d0;
    short8 o1, o2;
#pragma unroll
    for (int k = 0; k < 8; ++k) {
      const float c = cb[k], sn = sb[k];
      const float a = bf2f(x1[k]), v = bf2f(x2[k]);
      o1[k] = f2bf(a * c - v * sn);
      o2[k] = f2bf(v * c + a * sn);
    }
    *(short8*)p = o1;
    *(short8*)(p + 64) = o2;
  } else {
    b -= 2560;
    const int tx = threadIdx.x & 31, ty = threadIdx.x >> 5;
    const int c0 = (b & 31) * 32;        // V col tile (0..1023)
    const int r0 = (b >> 5) * 32;        // seq row tile (0..2047)
#pragma unroll
    for (int j = 0; j < 4; ++j)
      tile[ty + j * 8][tx] = qkv[(size_t)(r0 + ty + j * 8) * QS + 5120 + c0 + tx];
    __syncthreads();
#pragma unroll
    for (int j = 0; j < 4; ++j)
      vtg[(size_t)(c0 + ty + j * 8) * S_LEN + r0 + tx] = tile[tx][ty + j * 8];
  }
}

// SYNC with counted vmcnt AND counted lgkmcnt.
#define SYNC2(VM, LG)                                            \
  asm volatile("s_waitcnt vmcnt(" #VM ")" ::: "memory");         \
  __builtin_amdgcn_s_barrier();                                  \
  asm volatile("s_waitcnt lgkmcnt(" #LG ")" ::: "memory");       \
  __builtin_amdgcn_sched_barrier(0);                             \
  __builtin_amdgcn_s_setprio(1)

#define PH_END()                                                 \
  __builtin_amdgcn_s_setprio(0);                                 \
  __builtin_amdgcn_sched_barrier(0);                             \
  __builtin_amdgcn_s_barrier()

// ---------------- 256x192 2-PHASE GEMM for QKV (bf16 out), grid = 8x32 = 256 ---------
// (R15-proven: equal 3-phase flights for A and B; counted vm/lg ledger; tail peeled.)

__global__ __launch_bounds__(512, 2) void gemm192_k(
    const short* __restrict__ A, const short* __restrict__ BT,
    short* __restrict__ C, int M, int N, int K) {
  __shared__ __attribute__((aligned(16))) short ldsA[2][256 * 64];
  __shared__ __attribute__((aligned(16))) short ldsB[2][192 * 64];
  const int tid = threadIdx.x;
  const int l = tid & 63, w = tid >> 6;
  const int wrM = w >> 1, wcN = w & 1;     // 4M x 2N waves
  const int lrow = l & 15, lg = l >> 4;
  const int cofs[2] = {(lg ^ (lrow & 7)) << 3, ((4 + lg) ^ (lrow & 7)) << 3};
  (void)M;

  int bid = blockIdx.x;
  const int cpx = gridDim.x >> 3;          // XCD-chunked bijective (grid % 8 == 0)
  bid = (bid & 7) * cpx + (bid >> 3);
  const int ntn = N / 192;                 // 32
  const int m0 = (bid / ntn) << 8;
  const int n0 = (bid % ntn) * 192;

  auto stageA = [&](int tau) {
    const int k0 = tau << 6;
    short* ad = &ldsA[tau & 1][0];
#pragma unroll
    for (int it = 0; it < 4; ++it) {
      const int e = it * 512 + tid;
      const int row = e >> 3;
      const int js = (e & 7) ^ (row & 7);
      async16(A + (size_t)(m0 + row) * K + k0 + js * 8, ad + e * 8);
    }
  };
  auto stageB = [&](int tau) {
    const int k0 = tau << 6;
    short* bd = &ldsB[tau & 1][0];
#pragma unroll
    for (int it = 0; it < 3; ++it) {
      const int e = it * 512 + tid;
      const int row = e >> 3;
      const int js = (e & 7) ^ (row & 7);
      async16(BT + (size_t)(n0 + row) * K + k0 + js * 8, bd + e * 8);
    }
  };
  auto rdA = [&](short8 (&dst)[4][2], int b) {
    const short* p = &ldsA[b][0];
#pragma unroll
    for (int mi = 0; mi < 4; ++mi) {
      const int row = wrM * 64 + mi * 16 + lrow;
#pragma unroll
      for (int kk = 0; kk < 2; ++kk)
        dst[mi][kk] = *(const short8*)(p + row * 64 + cofs[kk]);
    }
  };
  auto rdB3 = [&](short8 (&dst)[3][2], int b, int h) {
    const short* p = &ldsB[b][0];
#pragma unroll
    for (int ni = 0; ni < 3; ++ni) {
      const int row = wcN * 96 + h * 48 + ni * 16 + lrow;
#pragma unroll
      for (int kk = 0; kk < 2; ++kk)
        dst[ni][kk] = *(const short8*)(p + row * 64 + cofs[kk]);
    }
  };

  f32x4 acc[4][6] = {};
  auto half24 = [&](short8 (&Af)[4][2], int h, short8 (&Bf)[3][2]) {
#pragma unroll
    for (int kk = 0; kk < 2; ++kk)
#pragma unroll
      for (int mi = 0; mi < 4; ++mi)
#pragma unroll
        for (int ni = 0; ni < 3; ++ni)
          acc[mi][h * 3 + ni] = __builtin_amdgcn_mfma_f32_16x16x32_bf16(
              Af[mi][kk], Bf[ni][kk], acc[mi][h * 3 + ni], 0, 0, 0);
  };

  short8 Aa[4][2], Ab[4][2], BF[3][2], BSa[3][2], BSb[3][2];

  // prologue: stage t0, t1; vm7 retires t0; read A(0), BF(0), BS(0)
  stageA(0); stageB(0); stageA(1); stageB(1);
  asm volatile("s_waitcnt vmcnt(7)" ::: "memory");
  __builtin_amdgcn_s_barrier();
  rdA(Aa, 0); rdB3(BF, 0, 0); rdB3(BSa, 0, 1);

  const int KT = K >> 6;  // 64 (even, >= 4)
  for (int u = 0; u < (KT - 2) / 2; ++u) {
    const int e = 2 * u;
    // ---- tile e (buf0, A=Aa, BS=BSa; read t+1 into Ab/BSb) ----
    SYNC2(7, 0);  stageA(e + 2); stageB(e + 2);
                  half24(Aa, 0, BF); PH_END();
    SYNC2(7, 0);  rdA(Ab, 1); rdB3(BF, 1, 0); rdB3(BSb, 1, 1);
                  half24(Aa, 1, BSa); PH_END();
    // ---- tile e+1 (buf1, A=Ab, BS=BSb; read t+2 into Aa/BSa) ----
    SYNC2(7, 0);  stageA(e + 3); stageB(e + 3);
                  half24(Ab, 0, BF); PH_END();
    SYNC2(7, 0);  rdA(Aa, 0); rdB3(BF, 0, 0); rdB3(BSa, 0, 1);
                  half24(Ab, 1, BSb); PH_END();
  }
  // ---- tail tile KT-2 (even: buf0, A=Aa, BS=BSa): no staging ----
  SYNC2(7, 0);  half24(Aa, 0, BF); PH_END();     // outstanding: KT-1's 7 -> pass
  SYNC2(0, 0);  rdA(Ab, 1); rdB3(BF, 1, 0); rdB3(BSb, 1, 1);   // vm0 drains KT-1
                half24(Aa, 1, BSa); PH_END();
  // ---- tile KT-1 (buf1, A=Ab, BS=BSb): all resident ----
  SYNC2(0, 0);  half24(Ab, 0, BF); PH_END();
  SYNC2(0, 0);  half24(Ab, 1, BSb); PH_END();

  // epilogue
  const int orow0 = m0 + wrM * 64 + lg * 4;
  const int ocol0 = n0 + wcN * 96 + lrow;
#pragma unroll
  for (int mi = 0; mi < 4; ++mi)
#pragma unroll
    for (int n = 0; n < 6; ++n)
#pragma unroll
      for (int r = 0; r < 4; ++r)
        C[(size_t)(orow0 + mi * 16 + r) * N + (ocol0 + n * 16)] = f2bf(acc[mi][n][r]);
}

// ---------------- 128x256 2-phase GEMM for WO (fp32 out), grid = 16x16 = 256 ---------

__global__ __launch_bounds__(512, 2) void gemm_wo2_k(
    const short* __restrict__ A, const short* __restrict__ BT,
    float* __restrict__ C, int M, int N, int K) {
  __shared__ __attribute__((aligned(16))) short ldsA[2][128 * 64];
  __shared__ __attribute__((aligned(16))) short ldsB[2][256 * 64];
  const int tid = threadIdx.x;
  const int l = tid & 63, w = tid >> 6;
  const int wrM = w >> 2, wcN = w & 3;     // 2M x 4N waves
  const int lrow = l & 15, lg = l >> 4;
  const int cofs[2] = {(lg ^ (lrow & 7)) << 3, ((4 + lg) ^ (lrow & 7)) << 3};
  (void)M;

  int bid = blockIdx.x;
  const int cpx = gridDim.x >> 3;
  bid = (bid & 7) * cpx + (bid >> 3);
  const int ntn = N >> 8;                  // 16
  const int m0 = (bid / ntn) << 7;
  const int n0 = (bid % ntn) << 8;

  auto stageA2 = [&](int tau) {
    const int k0 = tau << 6;
    short* ad = &ldsA[tau & 1][0];
#pragma unroll
    for (int it = 0; it < 2; ++it) {
      const int e = it * 512 + tid;
      const int row = e >> 3;
      const int js = (e & 7) ^ (row & 7);
      async16(A + (size_t)(m0 + row) * K + k0 + js * 8, ad + e * 8);
    }
  };
  auto stageB2 = [&](int tau) {
    const int k0 = tau << 6;
    short* bd = &ldsB[tau & 1][0];
#pragma unroll
    for (int it = 0; it < 4; ++it) {
      const int e = it * 512 + tid;
      const int row = e >> 3;
      const int js = (e & 7) ^ (row & 7);
      async16(BT + (size_t)(n0 + row) * K + k0 + js * 8, bd + e * 8);
    }
  };
  auto rdA = [&](short8 (&dst)[4][2], int b) {
    const short* p = &ldsA[b][0];
#pragma unroll
    for (int mi = 0; mi < 4; ++mi) {
      const int row = wrM * 64 + mi * 16 + lrow;
#pragma unroll
      for (int kk = 0; kk < 2; ++kk)
        dst[mi][kk] = *(const short8*)(p + row * 64 + cofs[kk]);
    }
  };
  auto rdB = [&](short8 (&dst)[2][2], int b, int h) {
    const short* p = &ldsB[b][0];
#pragma unroll
    for (int ni = 0; ni < 2; ++ni) {
      const int row = wcN * 64 + h * 32 + ni * 16 + lrow;
#pragma unroll
      for (int kk = 0; kk < 2; ++kk)
        dst[ni][kk] = *(const short8*)(p + row * 64 + cofs[kk]);
    }
  };

  f32x4 acc[4][4] = {};
  auto half = [&](short8 (&Af)[4][2], int h, short8 (&Bf)[2][2]) {
#pragma unroll
    for (int kk = 0; kk < 2; ++kk)
#pragma unroll
      for (int mi = 0; mi < 4; ++mi)
#pragma unroll
        for (int ni = 0; ni < 2; ++ni)
          acc[mi][h * 2 + ni] = __builtin_amdgcn_mfma_f32_16x16x32_bf16(
              Af[mi][kk], Bf[ni][kk], acc[mi][h * 2 + ni], 0, 0, 0);
  };

  short8 Aa[4][2], Ab[4][2], H0[2][2], H1a[2][2], H1b[2][2];

  // prologue
  stageA2(0); stageB2(0); stageA2(1); stageB2(1);
  asm volatile("s_waitcnt vmcnt(6)" ::: "memory");
  __builtin_amdgcn_s_barrier();
  rdA(Aa, 0); rdB(H0, 0, 0); rdB(H1a, 0, 1);

  const int KT = K >> 6;  // 64 (even, >= 4)
  for (int u = 0; u < (KT - 2) / 2; ++u) {
    const int e = 2 * u;
    // ---- tile e (buf0, A=Aa, H1=H1a) ----
    SYNC2(6, 0);  stageA2(e + 2); stageB2(e + 2);
                  half(Aa, 0, H0); PH_END();
    SYNC2(6, 0);  rdA(Ab, 1); rdB(H0, 1, 0); rdB(H1b, 1, 1);
                  half(Aa, 1, H1a); PH_END();
    // ---- tile e+1 (buf1, A=Ab, H1=H1b) ----
    SYNC2(6, 0);  stageA2(e + 3); stageB2(e + 3);
                  half(Ab, 0, H0); PH_END();
    SYNC2(6, 0);  rdA(Aa, 0); rdB(H0, 0, 0); rdB(H1a, 0, 1);
                  half(Ab, 1, H1b); PH_END();
  }
  // ---- tail tile KT-2 (buf0, A=Aa, H1=H1a): no staging ----
  SYNC2(6, 0);  half(Aa, 0, H0); PH_END();
  SYNC2(0, 0);  rdA(Ab, 1); rdB(H0, 1, 0); rdB(H1b, 1, 1);   // vm0 drains KT-1
                half(Aa, 1, H1a); PH_END();
  // ---- tile KT-1 (buf1, A=Ab, H1=H1b) ----
  SYNC2(0, 0);  half(Ab, 0, H0); PH_END();
  SYNC2(0, 0);  half(Ab, 1, H1b); PH_END();

  // epilogue (fp32)
  const int orow0 = m0 + wrM * 64 + lg * 4;
  const int ocol0 = n0 + wcN * 64 + lrow;
#pragma unroll
  for (int mi = 0; mi < 4; ++mi)
#pragma unroll
    for (int n = 0; n < 4; ++n)
#pragma unroll
      for (int r = 0; r < 4; ++r)
        C[(size_t)(orow0 + mi * 16 + r) * N + (ocol0 + n * 16)] = acc[mi][n][r];
}

// ---------------- flash attention (causal, GQA 4:1) ----------------

__global__ __launch_bounds__(256, 3) void attn_k(
    const short* __restrict__ Q, const short* __restrict__ Kc,
    const short* __restrict__ VTg, short* __restrict__ O) {
  __shared__ __attribute__((aligned(16))) short Ks[2][64 * 128];
  __shared__ __attribute__((aligned(16))) short Vt[2][128 * 64];
  __shared__ __attribute__((aligned(16))) short Ps[4][32 * 64];

  const int tid = threadIdx.x;
  const int w = tid >> 6, l = tid & 63;
  const int lrow = l & 15, lg = l >> 4;

  int b = blockIdx.x, h, qt;
  if (b < 256) { h = b >> 3; qt = 15 - (b & 7); }
  else { b -= 256; h = b >> 3; qt = b & 7; }
  const int kvh = h >> 2;
  const int qb0 = qt * 128;
  const int qrow0 = qb0 + w * 32;
  const int nkt = 2 * qt + 2;

  short8 qf[2][4];
#pragma unroll
  for (int nq = 0; nq < 2; ++nq) {
    const short* qp = Q + (size_t)(qrow0 + nq * 16 + lrow) * QS + h * HD;
#pragma unroll
    for (int c = 0; c < 4; ++c) qf[nq][c] = *(const short8*)(qp + c * 32 + lg * 8);
  }

  f32x4 o_acc[2][8] = {};
  float m[2] = {-INFINITY, -INFINITY};
  float lsum[2] = {0.f, 0.f};

  auto stage = [&](int kb, int buf) {
    short* kd = Ks[buf];
    short* vd = Vt[buf];
#pragma unroll
    for (int it = 0; it < 4; ++it) {
      const int e = it * 256 + tid;
      const int row = e >> 4, j = e & 15;
      const int jsrc = (j & 8) | ((j ^ row) & 7);
      async16(Kc + (size_t)(kb + row) * QS + kvh * HD + jsrc * 8, kd + e * 8);
    }
#pragma unroll
    for (int it = 0; it < 4; ++it) {
      const int e = it * 256 + tid;
      const int d = e >> 3, j = e & 7;
      const int jsrc = (j ^ d) & 7;
      async16(VTg + (size_t)(kvh * HD + d) * S_LEN + kb + jsrc * 8, vd + e * 8);
    }
  };

  stage(0, 0);
  int cur = 0;

  for (int kt = 0; kt < nkt; ++kt) {
    __syncthreads();
    if (kt + 1 < nkt) stage((kt + 1) * 64, cur ^ 1);
    const int kb = kt * 64;

    if (kb <= qrow0 + 31) {
      const char* ks = (const char*)Ks[cur];
      const char* vt = (const char*)Vt[cur];
      char* psb = (char*)Ps[w];

      f32x4 stq[4][2] = {};
#pragma unroll
      for (int c = 0; c < 4; ++c) {
#pragma unroll
        for (int mk = 0; mk < 4; ++mk) {
          const short8 kf = *(const short8*)(
              ks + (mk * 16 + lrow) * 256 + (((c * 4 + lg) ^ (lrow & 7)) << 4));
          stq[mk][0] = __builtin_amdgcn_mfma_f32_16x16x32_bf16(kf, qf[0][c], stq[mk][0], 0, 0, 0);
          stq[mk][1] = __builtin_amdgcn_mfma_f32_16x16x32_bf16(kf, qf[1][c], stq[mk][1], 0, 0, 0);
        }
      }

      const bool needmask = (kb + 63 > qrow0);
#pragma unroll
      for (int mk = 0; mk < 4; ++mk)
#pragma unroll
        for (int nq = 0; nq < 2; ++nq)
#pragma unroll
          for (int r = 0; r < 4; ++r) {
            float v = stq[mk][nq][r] * SCALE;
            if (needmask && (kb + mk * 16 + lg * 4 + r > qrow0 + nq * 16 + lrow))
              v = -INFINITY;
            stq[mk][nq][r] = v;
          }

      float vmax[2];
#pragma unroll
      for (int nq = 0; nq < 2; ++nq) {
        float v = stq[0][nq][0];
#pragma unroll
        for (int mk = 0; mk < 4; ++mk)
#pragma unroll
          for (int r = 0; r < 4; ++r) v = fmaxf(v, stq[mk][nq][r]);
        v = fmaxf(v, __shfl_xor(v, 16));
        v = fmaxf(v, __shfl_xor(v, 32));
        vmax[nq] = v;
      }

      const int small = (vmax[0] <= m[0] + 8.0f) && (vmax[1] <= m[1] + 8.0f);
      if (!__all(small)) {
        float al[2];
#pragma unroll
        for (int nq = 0; nq < 2; ++nq) {
          const float mn = fmaxf(m[nq], vmax[nq]);
          al[nq] = __expf(m[nq] - mn);
          m[nq] = mn;
          lsum[nq] *= al[nq];
        }
#pragma unroll
        for (int mmq = 0; mmq < 2; ++mmq)
#pragma unroll
          for (int r = 0; r < 4; ++r) {
            const float a = __shfl(al[mmq], lg * 4 + r);
#pragma unroll
            for (int d = 0; d < 8; ++d) o_acc[mmq][d][r] *= a;
          }
      }

      float rs[2] = {0.f, 0.f};
#pragma unroll
      for (int nq = 0; nq < 2; ++nq) {
#pragma unroll
        for (int mk = 0; mk < 4; ++mk) {
          const float p0 = __expf(stq[mk][nq][0] - m[nq]);
          const float p1 = __expf(stq[mk][nq][1] - m[nq]);
          const float p2 = __expf(stq[mk][nq][2] - m[nq]);
          const float p3 = __expf(stq[mk][nq][3] - m[nq]);
          rs[nq] += (p0 + p1) + (p2 + p3);
          __hip_bfloat16 b0 = __float2bfloat16(p0), b1 = __float2bfloat16(p1);
          __hip_bfloat16 b2 = __float2bfloat16(p2), b3 = __float2bfloat16(p3);
          short4 pk;
          pk.x = *(short*)&b0; pk.y = *(short*)&b1; pk.z = *(short*)&b2; pk.w = *(short*)&b3;
          const int q = nq * 16 + lrow;
          *(short4*)(psb + q * 128 + ((mk * 32 + lg * 8) ^ ((q & 7) << 4))) = pk;
        }
        float r2 = rs[nq];
        r2 += __shfl_xor(r2, 16);
        r2 += __shfl_xor(r2, 32);
        lsum[nq] += r2;
      }

#pragma unroll
      for (int cc = 0; cc < 2; ++cc) {
        const int chunk = ((cc * 4 + lg) ^ (lrow & 7)) << 4;
        const short8 pa0 = *(const short8*)(psb + lrow * 128 + chunk);
        const short8 pa1 = *(const short8*)(psb + (16 + lrow) * 128 + chunk);
#pragma unroll
        for (int d = 0; d < 8; ++d) {
          const short8 vf = *(const short8*)(vt + (d * 16 + lrow) * 128 + chunk);
          o_acc[0][d] = __builtin_amdgcn_mfma_f32_16x16x32_bf16(pa0, vf, o_acc[0][d], 0, 0, 0);
          o_acc[1][d] = __builtin_amdgcn_mfma_f32_16x16x32_bf16(pa1, vf, o_acc[1][d], 0, 0, 0);
        }
      }
    }
    cur ^= 1;
  }

  float linv[2] = {1.0f / lsum[0], 1.0f / lsum[1]};
#pragma unroll
  for (int mmq = 0; mmq < 2; ++mmq)
#pragma unroll
    for (int r = 0; r < 4; ++r) {
      const float li = __shfl(linv[mmq], lg * 4 + r);
      short* op = O + (size_t)(qrow0 + mmq * 16 + lg * 4 + r) * DIM + h * HD;
#pragma unroll
      for (int d = 0; d < 8; ++d)
        op[d * 16 + lrow] = f2bf(o_acc[mmq][d][r] * li);
    }
}

// ---------------- launch ----------------

extern "C" void kernel_launch(void* const* d_in, const int* in_sizes, int n_in,
                              void* d_out, int out_size, void* d_ws, size_t ws_size,
                              hipStream_t stream) {
  const float* x  = (const float*)d_in[0];
  const float* wq = (const float*)d_in[1];
  const float* wk = (const float*)d_in[2];
  const float* wv = (const float*)d_in[3];
  const float* wo = (const float*)d_in[4];
  float* out = (float*)d_out;
  (void)in_sizes; (void)n_in; (void)out_size; (void)ws_size;

  char* ws = (char*)d_ws;
  size_t off = 0;
  auto alloc = [&](size_t bytes) -> void* {
    void* p = ws + off;
    off += (bytes + 255) & ~(size_t)255;
    return p;
  };
  short* xb     = (short*)alloc((size_t)S_LEN * DIM * 2);
  short* wqkvT  = (short*)alloc((size_t)QS * DIM * 2);     // [6144][4096]
  short* woT    = (short*)alloc((size_t)DIM * DIM * 2);
  short* qkv    = (short*)alloc((size_t)S_LEN * QS * 2);   // [2048][6144]
  short* vtg    = (short*)alloc((size_t)KVD * S_LEN * 2);  // [1024][2048]
  short* ao     = (short*)alloc((size_t)S_LEN * DIM * 2);
  float* ct     = (float*)alloc((size_t)S_LEN * 64 * 4);
  float* st     = (float*)alloc((size_t)S_LEN * 64 * 4);

  rope_tables_k<<<(S_LEN * 64) / 256, 256, 0, stream>>>(ct, st);
  cast_f32_bf16_k<<<(S_LEN * DIM / 4) / 256, 256, 0, stream>>>(x, xb, S_LEN * DIM / 4);
  prep_w_k<<<dim3(10240), dim3(256), 0, stream>>>(wq, wk, wv, wo, wqkvT, woT);

  // fused QKV projection: [2048][6144], 256x192 2-phase -> grid 256 (full machine)
  gemm192_k<<<dim3((S_LEN / 256) * (QS / 192)), 512, 0, stream>>>(
      xb, wqkvT, qkv, S_LEN, QS, DIM);

  // fused vectorized RoPE (q+k) + V^T transpose, one launch
  rope_vt_k<<<dim3(4608), 256, 0, stream>>>(qkv, ct, st, vtg);

  attn_k<<<dim3(512), 256, 0, stream>>>(qkv, qkv + 4096, vtg, ao);

  // output projection: 128x256 2-phase counted pipeline -> grid 256 (full machine)
  gemm_wo2_k<<<dim3((S_LEN / 128) * (DIM / 256)), 512, 0, stream>>>(
      ao, woT, out, S_LEN, DIM, DIM);
}